// Round 9
// baseline (517.295 us; speedup 1.0000x reference)
//
#include <hip/hip_runtime.h>
#include <hip/hip_bf16.h>
#include <stdint.h>

static constexpr int N_ = 16384;
static constexpr int D_ = 2048;
static constexpr float SCALE_R = 1.0f / 16.0f;            // 1/sqrt(HD=256)
static constexpr float SCALE_W = 0.02209708691207961f;    // 1/sqrt(D=2048)

typedef __bf16 bf16x8 __attribute__((ext_vector_type(8)));
typedef float f32x4 __attribute__((ext_vector_type(4)));

__device__ __forceinline__ unsigned short f2bf(float f) {
  unsigned int u = __float_as_uint(f);
  unsigned int r = (u + 0x7fff + ((u >> 16) & 1)) >> 16;  // RNE
  return (unsigned short)r;
}

__device__ __forceinline__ void lds_load16(void* lds, const void* g) {
  __builtin_amdgcn_global_load_lds(
      (const __attribute__((address_space(1))) uint32_t*)(uintptr_t)g,
      (__attribute__((address_space(3))) uint32_t*)(uint32_t)(uintptr_t)lds,
      16, 0, 0);
}

// ---- K1: k = memory@Wrk.T, v = memory@Wrv.T, wq = memory@Wwq.T  (each [8][2048])
__global__ __launch_bounds__(256) void k_kvwq(
    const float* __restrict__ mem, const float* __restrict__ wrk,
    const float* __restrict__ wrv, const float* __restrict__ wwq,
    float* __restrict__ kbuf, float* __restrict__ vbuf, float* __restrict__ wqbuf) {
  int gw = (blockIdx.x * 256 + threadIdx.x) >> 6;  // 0..6143
  int lane = threadIdx.x & 63;
  int which = gw >> 11;
  int j = gw & 2047;
  const float* W = which == 0 ? wrk : (which == 1 ? wrv : wwq);
  float* O = which == 0 ? kbuf : (which == 1 ? vbuf : wqbuf);
  const f32x4* Wrow = (const f32x4*)(W + (size_t)j * D_);
  const f32x4* M4 = (const f32x4*)mem;
  float acc[8];
#pragma unroll
  for (int kk = 0; kk < 8; ++kk) acc[kk] = 0.f;
#pragma unroll
  for (int t = 0; t < 8; ++t) {
    f32x4 w4 = Wrow[lane + 64 * t];
#pragma unroll
    for (int kk = 0; kk < 8; ++kk) {
      f32x4 m4 = M4[kk * 512 + lane + 64 * t];
      acc[kk] += w4[0] * m4[0] + w4[1] * m4[1] + w4[2] * m4[2] + w4[3] * m4[3];
    }
  }
#pragma unroll
  for (int off = 1; off < 64; off <<= 1)
#pragma unroll
    for (int kk = 0; kk < 8; ++kk) acc[kk] += __shfl_xor(acc[kk], off, 64);
  if (lane == 0) {
#pragma unroll
    for (int kk = 0; kk < 8; ++kk) O[kk * D_ + j] = acc[kk];
  }
}

// ---- K2: PRT[80][2048] fp32: rows 0..63 = P (scaled 1/16), rows 64..71 = R
__global__ __launch_bounds__(256) void k_pr(
    const float* __restrict__ wrq, const float* __restrict__ wwk,
    const float* __restrict__ kbuf, const float* __restrict__ wqbuf,
    float* __restrict__ PRT) {
  int b = blockIdx.x;
  int tid = threadIdx.x;
  if (b < 64) {
    int ic = b >> 3, h = b & 7;
    int i = ic * 256 + tid;
    float acc[8];
#pragma unroll
    for (int kk = 0; kk < 8; ++kk) acc[kk] = 0.f;
    for (int jj = 0; jj < 256; ++jj) {
      int j = h * 256 + jj;
      float wv = wrq[(size_t)j * D_ + i];
#pragma unroll
      for (int kk = 0; kk < 8; ++kk) acc[kk] += wv * kbuf[kk * D_ + j];
    }
#pragma unroll
    for (int kk = 0; kk < 8; ++kk) PRT[(h * 8 + kk) * D_ + i] = acc[kk] * SCALE_R;
  } else {
    int bb = b - 64;
    int ic = bb >> 3, jc = bb & 7;
    int i = ic * 256 + tid;
    float acc[8];
#pragma unroll
    for (int kk = 0; kk < 8; ++kk) acc[kk] = 0.f;
    for (int jj = 0; jj < 256; ++jj) {
      int j = jc * 256 + jj;
      float wv = wwk[(size_t)j * D_ + i];
#pragma unroll
      for (int kk = 0; kk < 8; ++kk) acc[kk] += wv * wqbuf[kk * D_ + j];
    }
#pragma unroll
    for (int kk = 0; kk < 8; ++kk) atomicAdd(&PRT[(64 + kk) * D_ + i], acc[kk] * SCALE_W);
  }
}

// ---- K_prep: fused  Wp = bf16(gamma⊙Wout row),  c1[j]=Σ gamma*W, c2[j]=Σ beta*W
__global__ __launch_bounds__(256) void k_prep(const float* __restrict__ wro,
                                              const float* __restrict__ gamma,
                                              const float* __restrict__ beta,
                                              unsigned short* __restrict__ wp,
                                              float* __restrict__ c1, float* __restrict__ c2) {
  __shared__ float red1[4], red2[4];
  int j = blockIdx.x;
  int tid = threadIdx.x;
  int d = tid * 8;
  const float* src = wro + (size_t)j * D_ + d;
  f32x4 a = *(const f32x4*)src, b = *(const f32x4*)(src + 4);
  f32x4 g0 = *(const f32x4*)(gamma + d), g1 = *(const f32x4*)(gamma + d + 4);
  f32x4 b0 = *(const f32x4*)(beta + d), b1 = *(const f32x4*)(beta + d + 4);
  ushort4 o0, o1;
  o0.x = f2bf(a[0] * g0[0]); o0.y = f2bf(a[1] * g0[1]);
  o0.z = f2bf(a[2] * g0[2]); o0.w = f2bf(a[3] * g0[3]);
  o1.x = f2bf(b[0] * g1[0]); o1.y = f2bf(b[1] * g1[1]);
  o1.z = f2bf(b[2] * g1[2]); o1.w = f2bf(b[3] * g1[3]);
  unsigned short* dst = wp + (size_t)j * D_ + d;
  *(ushort4*)dst = o0;
  *(ushort4*)(dst + 4) = o1;
  float s1 = a[0] * g0[0] + a[1] * g0[1] + a[2] * g0[2] + a[3] * g0[3] +
             b[0] * g1[0] + b[1] * g1[1] + b[2] * g1[2] + b[3] * g1[3];
  float s2 = a[0] * b0[0] + a[1] * b0[1] + a[2] * b0[2] + a[3] * b0[3] +
             b[0] * b1[0] + b[1] * b1[1] + b[2] * b1[2] + b[3] * b1[3];
#pragma unroll
  for (int off = 1; off < 64; off <<= 1) {
    s1 += __shfl_xor(s1, off, 64);
    s2 += __shfl_xor(s2, off, 64);
  }
  int wave = tid >> 6, lane = tid & 63;
  if (lane == 0) { red1[wave] = s1; red2[wave] = s2; }
  __syncthreads();
  if (tid == 0) {
    c1[j] = red1[0] + red1[1] + red1[2] + red1[3];
    c2[j] = red2[0] + red2[1] + red2[2] + red2[3];
  }
}

// ---- K3: fused MFMA S-GEMM + in-reg PER-HEAD softmax + ro + (raw ro, mu, rstd) + u-partials
__global__ __launch_bounds__(256) void k_main(
    const float* __restrict__ hidden, const float* __restrict__ PRT,
    const float* __restrict__ vbuf,
    unsigned short* __restrict__ Xhat, float* __restrict__ mu_out,
    float* __restrict__ rstd_out,
    float* __restrict__ upart, float* __restrict__ Zpart) {
  __shared__ unsigned short Ah[2][64 * 64];   // 16 KB, XOR-swizzled bf16 hidden tile
  __shared__ unsigned short Bh[2][80 * 64];   // 20 KB, XOR-swizzled bf16 PRT tile
  __shared__ unsigned short attnL[64 * 64];   // 8 KB bf16 attn
  __shared__ float e8lds[64][8];              // 2 KB
  const int tid = threadIdx.x;
  const int row0 = blockIdx.x * 64;
  const int wave = tid >> 6, lane = tid & 63;
  const int fl = lane & 15, fk = lane >> 4;
  const int ar = tid >> 2, acg = tid & 3;     // A staging: row, 16-col group

  f32x4 sA0[4], sB0[5], sA1[4], sB1[5];

  auto loadAB = [&](f32x4* a, f32x4* b, int t) {
    const float* srcA = hidden + (size_t)(row0 + ar) * D_ + t * 64 + acg * 16;
#pragma unroll
    for (int q = 0; q < 4; ++q) a[q] = *(const f32x4*)(srcA + q * 4);
#pragma unroll
    for (int p = 0; p < 5; ++p) {
      int e = p * 256 + tid;
      int rB = e >> 4, c4 = e & 15;
      b[p] = *(const f32x4*)(PRT + (size_t)rB * D_ + t * 64 + c4 * 4);
    }
  };
  auto writeAB = [&](int buf, f32x4* a, f32x4* b) {
#pragma unroll
    for (int hh = 0; hh < 2; ++hh) {
      f32x4 x = a[hh * 2], y = a[hh * 2 + 1];
      ushort4 o0 = {f2bf(x[0]), f2bf(x[1]), f2bf(x[2]), f2bf(x[3])};
      ushort4 o1 = {f2bf(y[0]), f2bf(y[1]), f2bf(y[2]), f2bf(y[3])};
      int idx = (ar * 64 + acg * 16 + hh * 8) ^ ((ar & 7) << 3);
      *(ushort4*)&Ah[buf][idx] = o0;
      *(ushort4*)&Ah[buf][idx + 4] = o1;
    }
#pragma unroll
    for (int p = 0; p < 5; ++p) {
      int e = p * 256 + tid;
      int rB = e >> 4, c4 = e & 15;
      ushort4 o = {f2bf(b[p][0]), f2bf(b[p][1]), f2bf(b[p][2]), f2bf(b[p][3])};
      int idx = (rB * 64 + c4 * 4) ^ ((rB & 7) << 3);
      *(ushort4*)&Bh[buf][idx] = o;
    }
  };

  f32x4 acc[5];
#pragma unroll
  for (int n = 0; n < 5; ++n) acc[n] = (f32x4){0.f, 0.f, 0.f, 0.f};

  auto compute = [&](int buf) {
#pragma unroll
    for (int kk = 0; kk < 2; ++kk) {
      int klo = kk * 32 + fk * 8;
      bf16x8 af = *(const bf16x8*)&Ah[buf][((wave * 16 + fl) * 64 + klo) ^ ((fl & 7) << 3)];
#pragma unroll
      for (int n = 0; n < 5; ++n) {
        bf16x8 bf = *(const bf16x8*)&Bh[buf][((n * 16 + fl) * 64 + klo) ^ ((fl & 7) << 3)];
        acc[n] = __builtin_amdgcn_mfma_f32_16x16x32_bf16(af, bf, acc[n], 0, 0, 0);
      }
    }
  };

  loadAB(sA0, sB0, 0);
  loadAB(sA1, sB1, 1);
  for (int t = 0; t < 32; t += 2) {
    writeAB(0, sA0, sB0);
    if (t + 2 < 32) loadAB(sA0, sB0, t + 2);
    __syncthreads();
    compute(0);
    writeAB(1, sA1, sB1);
    if (t + 3 < 32) loadAB(sA1, sB1, t + 3);
    __syncthreads();
    compute(1);
  }

  // ---- in-register PER-HEAD softmax.
#pragma unroll
  for (int r = 0; r < 4; ++r) {
    int rowl = wave * 16 + fk * 4 + r;
#pragma unroll
    for (int n = 0; n < 4; ++n) {
      float sv = acc[n][r];
      float m = sv;
      m = fmaxf(m, __shfl_xor(m, 1, 64));
      m = fmaxf(m, __shfl_xor(m, 2, 64));
      m = fmaxf(m, __shfl_xor(m, 4, 64));
      float e = __expf(sv - m);
      float ssum = e;
      ssum += __shfl_xor(ssum, 1, 64);
      ssum += __shfl_xor(ssum, 2, 64);
      ssum += __shfl_xor(ssum, 4, 64);
      attnL[rowl * 64 + n * 16 + fl] = f2bf(e / ssum);
    }
    if (fl < 8) e8lds[rowl][fl] = __expf(acc[4][r]);  // write-softmax numerator (|s_w|<<1)
  }
  __syncthreads();

  // ---- ro phase: per wave 16 rows; chunk c = head, d = c*256 + lane*4
  float ssum[16], ssq[16];
#pragma unroll
  for (int rw = 0; rw < 16; ++rw) { ssum[rw] = 0.f; ssq[rw] = 0.f; }
#pragma unroll
  for (int c = 0; c < 8; ++c) {
    int d0 = c * 256 + lane * 4;
    f32x4 vv[8];
#pragma unroll
    for (int kk = 0; kk < 8; ++kk) vv[kk] = *(const f32x4*)(vbuf + kk * D_ + d0);
#pragma unroll
    for (int rw = 0; rw < 16; ++rw) {
      bf16x8 at = *(const bf16x8*)&attnL[(wave * 16 + rw) * 64 + c * 8];
      f32x4 ro = (float)at[0] * vv[0] + (float)at[1] * vv[1] +
                 (float)at[2] * vv[2] + (float)at[3] * vv[3] +
                 (float)at[4] * vv[4] + (float)at[5] * vv[5] +
                 (float)at[6] * vv[6] + (float)at[7] * vv[7];
      ssum[rw] += ro[0] + ro[1] + ro[2] + ro[3];
      ssq[rw] += ro[0] * ro[0] + ro[1] * ro[1] + ro[2] * ro[2] + ro[3] * ro[3];
      ushort4 o = {f2bf(ro[0]), f2bf(ro[1]), f2bf(ro[2]), f2bf(ro[3])};
      *(ushort4*)(Xhat + (size_t)(row0 + wave * 16 + rw) * D_ + d0) = o;
    }
  }
  float muv = 0.f, rstdv = 0.f;
#pragma unroll
  for (int rw = 0; rw < 16; ++rw) {
    float s = ssum[rw], q = ssq[rw];
#pragma unroll
    for (int off = 1; off < 64; off <<= 1) {
      s += __shfl_xor(s, off, 64);
      q += __shfl_xor(q, off, 64);
    }
    float m = s * (1.f / 2048.f);
    float var = q * (1.f / 2048.f) - m * m;
    float rs = rsqrtf(var + 1e-5f);
    if (lane == rw) { muv = m; rstdv = rs; }
  }
  if (lane < 16) {
    mu_out[row0 + wave * 16 + lane] = muv;
    rstd_out[row0 + wave * 16 + lane] = rstdv;
  }
  __syncthreads();

  // ---- u-partials: wave owns 512-wide d-range, 8-row load strips
  for (int dt = 0; dt < 2; ++dt) {
    int d0 = wave * 512 + dt * 256 + lane * 4;
    f32x4 ua[8];
#pragma unroll
    for (int kk = 0; kk < 8; ++kk) ua[kk] = (f32x4){0.f, 0.f, 0.f, 0.f};
    for (int r8 = 0; r8 < 64; r8 += 8) {
      f32x4 hv[8];
#pragma unroll
      for (int q = 0; q < 8; ++q)
        hv[q] = *(const f32x4*)(hidden + (size_t)(row0 + r8 + q) * D_ + d0);
#pragma unroll
      for (int q = 0; q < 8; ++q) {
        f32x4 e0 = *(const f32x4*)&e8lds[r8 + q][0];
        f32x4 e1 = *(const f32x4*)&e8lds[r8 + q][4];
        ua[0] += e0[0] * hv[q]; ua[1] += e0[1] * hv[q];
        ua[2] += e0[2] * hv[q]; ua[3] += e0[3] * hv[q];
        ua[4] += e1[0] * hv[q]; ua[5] += e1[1] * hv[q];
        ua[6] += e1[2] * hv[q]; ua[7] += e1[3] * hv[q];
      }
    }
#pragma unroll
    for (int kk = 0; kk < 8; ++kk)
      *(f32x4*)(upart + ((size_t)blockIdx.x * 8 + kk) * D_ + d0) = ua[kk];
  }
  if (tid < 8) {
    float z = 0.f;
    for (int r = 0; r < 64; ++r) z += e8lds[r][tid];
    Zpart[blockIdx.x * 8 + tid] = z;
  }
}

// ---- K4: reduce u-partials, t = u/Z  ([8][2048])
__global__ __launch_bounds__(256) void k_ured(const float* __restrict__ upart,
                                              const float* __restrict__ Zpart,
                                              float* __restrict__ tbuf) {
  int g = blockIdx.x * 256 + threadIdx.x;  // 0..16383
  int kk = g >> 11, d = g & 2047;
  float z = 0.f;
  for (int b = 0; b < 256; ++b) z += Zpart[b * 8 + kk];
  float u = 0.f;
  for (int b = 0; b < 256; ++b) u += upart[((size_t)b * 8 + kk) * 2048 + d];
  tbuf[g] = u / z;
}

// ---- K5b: new_memory = (1-wg)*memory + wg * (t @ Wwv.T)
__global__ __launch_bounds__(256) void k_newmem(
    const float* __restrict__ tbuf, const float* __restrict__ wwv,
    const float* __restrict__ mem, const float* __restrict__ wgate,
    float* __restrict__ out_mem) {
  int j = (blockIdx.x * 256 + threadIdx.x) >> 6;  // 0..2047
  int lane = threadIdx.x & 63;
  const f32x4* Wrow = (const f32x4*)(wwv + (size_t)j * D_);
  const f32x4* T4 = (const f32x4*)tbuf;
  float acc[8];
#pragma unroll
  for (int kk = 0; kk < 8; ++kk) acc[kk] = 0.f;
#pragma unroll
  for (int t = 0; t < 8; ++t) {
    f32x4 w4 = Wrow[lane + 64 * t];
#pragma unroll
    for (int kk = 0; kk < 8; ++kk) {
      f32x4 t4 = T4[kk * 512 + lane + 64 * t];
      acc[kk] += w4[0] * t4[0] + w4[1] * t4[1] + w4[2] * t4[2] + w4[3] * t4[3];
    }
  }
#pragma unroll
  for (int off = 1; off < 64; off <<= 1)
#pragma unroll
    for (int kk = 0; kk < 8; ++kk) acc[kk] += __shfl_xor(acc[kk], off, 64);
  if (lane == 0) {
    float wg = 1.f / (1.f + __expf(-wgate[0]));
#pragma unroll
    for (int kk = 0; kk < 8; ++kk)
      out_mem[kk * D_ + j] = (1.f - wg) * mem[kk * D_ + j] + wg * acc[kk];
  }
}

// ---- K5: result = hidden + g*(rstd*(ro@W'^T) - rstd*mu*c1 + c2)
// m201 8-phase port: 256x256, BK=64, dbuf 128 KB, 8 waves (2Mx4N), 4 phases
// per K-tile, each {ds_read subtile | stage 1 chunk -> s_barrier -> setprio +
// 16 MFMA -> s_barrier}. Counted vmcnt NEVER 0 until last tile:
//   stage order t->t+1: [cA0 (A rows read@P0), cB0 (B n01), cB1 (B n23), cA1
//   (A rows read@P2)]; vmcnt(2)@P3 completes cA0,cB0,cB1; vmcnt(4)@P1
//   completes prior tile's cA1 (outstanding = cA1 + cA0' + cB0' = 6).
// "memory" clobber on vmcnt asm fences P2's ds_read from hoisting above its
// wait. Granule-XOR swizzle both sides (R4-verified 0 conflicts).
__global__ __launch_bounds__(512, 2) void k_gemm(
    const unsigned short* __restrict__ A,  // raw ro bf16 [16384][2048]
    const unsigned short* __restrict__ B,  // W' bf16 [2048][2048] (row j = out col)
    const float* __restrict__ hidden, const float* __restrict__ gate,
    const float* __restrict__ mu, const float* __restrict__ rstd,
    const float* __restrict__ c1, const float* __restrict__ c2,
    float* __restrict__ out) {
  __shared__ unsigned short As[2][256 * 64];  // 64 KB
  __shared__ unsigned short Bs[2][256 * 64];  // 64 KB
  const int tid = threadIdx.x;                 // 0..511
  const int bm = blockIdx.x >> 3, bn = blockIdx.x & 7;  // bn%8 -> B slab L2-resident/XCD
  const int row0 = bm * 256, col0 = bn * 256;
  const int wave = tid >> 6, lane = tid & 63;
  const int wr = wave >> 2, wc = wave & 3;     // per-wave 128 rows x 64 cols
  const int fl = lane & 15, fk = lane >> 4;
  const int sgl = tid & 7;                     // dest granule (16B)
  const int sgs = sgl ^ ((tid >> 3) & 7);      // pre-swizzled source granule

  // chunk staging: 2 gload_lds/thread, 128 rows each. Row maps chosen so each
  // chunk's rows share one read-deadline across all waves; (row&7)==((tid>>3)&7)
  // in every map, so the swizzle key matches the ds_read key.
  auto stageA = [&](int e, int kt, int which) {  // which 0: rows {0-63,128-191}; 1: +64
#pragma unroll
    for (int l = 0; l < 2; ++l) {
      int cr = (tid >> 3) + l * 64;
      int row = cr + ((cr >> 6) << 6) + (which << 6);
      lds_load16(&As[e][row * 64 + sgl * 8], A + (size_t)(row0 + row) * D_ + kt * 64 + sgs * 8);
    }
  };
  auto stageB = [&](int e, int kt, int which) {  // which 0: rows {0-31,64-95,...}; 1: +32
#pragma unroll
    for (int l = 0; l < 2; ++l) {
      int cr = (tid >> 3) + l * 64;
      int row = (cr & 31) + ((cr >> 5) << 6) + (which << 5);
      lds_load16(&Bs[e][row * 64 + sgl * 8], B + (size_t)(col0 + row) * D_ + kt * 64 + sgs * 8);
    }
  };

  f32x4 acc[8][4];
#pragma unroll
  for (int m = 0; m < 8; ++m)
#pragma unroll
    for (int n = 0; n < 4; ++n) acc[m][n] = (f32x4){0.f, 0.f, 0.f, 0.f};

  // prologue: stage tile 0 in steady-state order, complete all but cA1
  stageA(0, 0, 0); stageB(0, 0, 0); stageB(0, 0, 1); stageA(0, 0, 1);
  asm volatile("s_waitcnt vmcnt(2)" ::: "memory");
  __builtin_amdgcn_s_barrier();

  bf16x8 a[4][2], b[4][2];
  for (int t = 0; t < 32; ++t) {
    const int d = t & 1, e = d ^ 1;
    const bool pf = (t + 1) < 32;
    // ---- P0: reads A m0-3 + B n0-1 (12 ds_read); MFMA Q(m0-3, n0-1)
#pragma unroll
    for (int m = 0; m < 4; ++m) {
      int row = wr * 128 + m * 16 + fl;
#pragma unroll
      for (int kk = 0; kk < 2; ++kk)
        a[m][kk] = *(const bf16x8*)&As[d][row * 64 + (((kk * 4 + fk) ^ (fl & 7)) * 8)];
    }
#pragma unroll
    for (int n = 0; n < 2; ++n) {
      int row = wc * 64 + n * 16 + fl;
#pragma unroll
      for (int kk = 0; kk < 2; ++kk)
        b[n][kk] = *(const bf16x8*)&Bs[d][row * 64 + (((kk * 4 + fk) ^ (fl & 7)) * 8)];
    }
    if (pf) stageA(e, t + 1, 0);
    __builtin_amdgcn_s_barrier();
    __builtin_amdgcn_s_setprio(1);
#pragma unroll
    for (int m = 0; m < 4; ++m)
#pragma unroll
      for (int n = 0; n < 2; ++n)
#pragma unroll
        for (int kk = 0; kk < 2; ++kk)
          acc[m][n] = __builtin_amdgcn_mfma_f32_16x16x32_bf16(a[m][kk], b[n][kk], acc[m][n], 0, 0, 0);
    __builtin_amdgcn_s_setprio(0);
    __builtin_amdgcn_s_barrier();
    // ---- P1: reads B n2-3 (4); vmcnt completes prior cA1; MFMA Q(m0-3, n2-3)
#pragma unroll
    for (int n = 2; n < 4; ++n) {
      int row = wc * 64 + n * 16 + fl;
#pragma unroll
      for (int kk = 0; kk < 2; ++kk)
        b[n][kk] = *(const bf16x8*)&Bs[d][row * 64 + (((kk * 4 + fk) ^ (fl & 7)) * 8)];
    }
    if (pf) {
      stageB(e, t + 1, 0);
      asm volatile("s_waitcnt vmcnt(4)" ::: "memory");
    } else {
      asm volatile("s_waitcnt vmcnt(0)" ::: "memory");
    }
    __builtin_amdgcn_s_barrier();
    __builtin_amdgcn_s_setprio(1);
#pragma unroll
    for (int m = 0; m < 4; ++m)
#pragma unroll
      for (int n = 2; n < 4; ++n)
#pragma unroll
        for (int kk = 0; kk < 2; ++kk)
          acc[m][n] = __builtin_amdgcn_mfma_f32_16x16x32_bf16(a[m][kk], b[n][kk], acc[m][n], 0, 0, 0);
    __builtin_amdgcn_s_setprio(0);
    __builtin_amdgcn_s_barrier();
    // ---- P2: reads A m4-7 (8, after cA1's vmcnt); MFMA Q(m4-7, n0-1)
#pragma unroll
    for (int m = 0; m < 4; ++m) {
      int row = wr * 128 + (m + 4) * 16 + fl;
#pragma unroll
      for (int kk = 0; kk < 2; ++kk)
        a[m][kk] = *(const bf16x8*)&As[d][row * 64 + (((kk * 4 + fk) ^ (fl & 7)) * 8)];
    }
    if (pf) stageB(e, t + 1, 1);
    __builtin_amdgcn_s_barrier();
    __builtin_amdgcn_s_setprio(1);
#pragma unroll
    for (int m = 0; m < 4; ++m)
#pragma unroll
      for (int n = 0; n < 2; ++n)
#pragma unroll
        for (int kk = 0; kk < 2; ++kk)
          acc[m + 4][n] = __builtin_amdgcn_mfma_f32_16x16x32_bf16(a[m][kk], b[n][kk], acc[m + 4][n], 0, 0, 0);
    __builtin_amdgcn_s_setprio(0);
    __builtin_amdgcn_s_barrier();
    // ---- P3: stage cA1 + vmcnt(2) (completes cA0,cB0,cB1 of t+1); MFMA Q(m4-7, n2-3)
    if (pf) {
      stageA(e, t + 1, 1);
      asm volatile("s_waitcnt vmcnt(2)" ::: "memory");
    }
    __builtin_amdgcn_s_barrier();
    __builtin_amdgcn_s_setprio(1);
#pragma unroll
    for (int m = 0; m < 4; ++m)
#pragma unroll
      for (int n = 2; n < 4; ++n)
#pragma unroll
        for (int kk = 0; kk < 2; ++kk)
          acc[m + 4][n] = __builtin_amdgcn_mfma_f32_16x16x32_bf16(a[m][kk], b[n][kk], acc[m + 4][n], 0, 0, 0);
    __builtin_amdgcn_s_setprio(0);
    __builtin_amdgcn_s_barrier();
  }

  float g = 1.f / (1.f + __expf(-gate[0]));
#pragma unroll
  for (int n = 0; n < 4; ++n) {
    int col = col0 + wc * 64 + n * 16 + fl;
    float C1 = c1[col] * g, C2 = c2[col] * g;
#pragma unroll
    for (int m = 0; m < 8; ++m)
#pragma unroll
      for (int r = 0; r < 4; ++r) {
        int row = row0 + wr * 128 + m * 16 + fk * 4 + r;
        float RS = rstd[row], MU = mu[row];
        size_t idx = (size_t)row * D_ + col;
        out[idx] = hidden[idx] + g * RS * acc[m][n][r] - RS * MU * C1 + C2;
      }
  }
}

extern "C" void kernel_launch(void* const* d_in, const int* in_sizes, int n_in,
                              void* d_out, int out_size, void* d_ws, size_t ws_size,
                              hipStream_t stream) {
  const float* hidden = (const float*)d_in[0];
  const float* mem    = (const float*)d_in[1];
  const float* wrq = (const float*)d_in[2];
  const float* wrk = (const float*)d_in[3];
  const float* wrv = (const float*)d_in[4];
  const float* wro = (const float*)d_in[5];
  const float* wwq = (const float*)d_in[6];
  const float* wwk = (const float*)d_in[7];
  const float* wwv = (const float*)d_in[8];
  const float* gamma = (const float*)d_in[9];
  const float* beta  = (const float*)d_in[10];
  const float* gate  = (const float*)d_in[11];
  const float* wgate = (const float*)d_in[12];
  float* out = (float*)d_out;

  char* ws = (char*)d_ws;
  float* kbuf  = (float*)(ws);                    // 64 KB; reused as mu after k_pr
  float* vbuf  = (float*)(ws + (64 << 10));       // 64 KB
  float* wqbuf = (float*)(ws + (128 << 10));      // 64 KB; reused as rstd after k_pr
  float* PRT   = (float*)(ws + (192 << 10));      // 640 KB fp32
  float* tbuf  = (float*)(ws + (832 << 10));      // 64 KB
  float* Zpart = (float*)(ws + (896 << 10));      // 8 KB
  float* c1    = (float*)(ws + (904 << 10));      // 8 KB
  float* c2    = (float*)(ws + (912 << 10));      // 8 KB
  float* upart = (float*)(ws + (960ull << 10));   // 16 MB
  unsigned short* Wp   = (unsigned short*)(ws + (960ull << 10) + (16ull << 20));  // 8 MB
  unsigned short* Xhat = (unsigned short*)(ws + (960ull << 10) + (24ull << 20));  // 64 MB
  float* mu   = kbuf;    // overlay: kbuf dead after k_pr
  float* rstd = wqbuf;   // overlay: wqbuf dead after k_pr

  hipMemsetAsync(PRT, 0, 80 * 2048 * sizeof(float), stream);
  k_prep<<<2048, 256, 0, stream>>>(wro, gamma, beta, Wp, c1, c2);
  k_kvwq<<<1536, 256, 0, stream>>>(mem, wrk, wrv, wwq, kbuf, vbuf, wqbuf);
  k_pr<<<128, 256, 0, stream>>>(wrq, wwk, kbuf, wqbuf, PRT);
  k_main<<<256, 256, 0, stream>>>(hidden, PRT, vbuf, Xhat, mu, rstd, upart, Zpart);
  k_ured<<<64, 256, 0, stream>>>(upart, Zpart, tbuf);
  k_newmem<<<512, 256, 0, stream>>>(tbuf, wwv, mem, wgate, out + (size_t)N_ * D_);
  k_gemm<<<512, 512, 0, stream>>>(Xhat, Wp, hidden, gate, mu, rstd, c1, c2, out);
}

// Round 10
// 343.245 us; speedup vs baseline: 1.5071x; 1.5071x over previous
//
#include <hip/hip_runtime.h>
#include <hip/hip_bf16.h>
#include <stdint.h>

static constexpr int N_ = 16384;
static constexpr int D_ = 2048;
static constexpr float SCALE_R = 1.0f / 16.0f;            // 1/sqrt(HD=256)
static constexpr float SCALE_W = 0.02209708691207961f;    // 1/sqrt(D=2048)

typedef __bf16 bf16x8 __attribute__((ext_vector_type(8)));
typedef float f32x4 __attribute__((ext_vector_type(4)));

__device__ __forceinline__ unsigned short f2bf(float f) {
  unsigned int u = __float_as_uint(f);
  unsigned int r = (u + 0x7fff + ((u >> 16) & 1)) >> 16;  // RNE
  return (unsigned short)r;
}

__device__ __forceinline__ void lds_load16(void* lds, const void* g) {
  __builtin_amdgcn_global_load_lds(
      (const __attribute__((address_space(1))) uint32_t*)(uintptr_t)g,
      (__attribute__((address_space(3))) uint32_t*)(uint32_t)(uintptr_t)lds,
      16, 0, 0);
}

// ---- K1: k = memory@Wrk.T, v = memory@Wrv.T, wq = memory@Wwq.T  (each [8][2048])
__global__ __launch_bounds__(256) void k_kvwq(
    const float* __restrict__ mem, const float* __restrict__ wrk,
    const float* __restrict__ wrv, const float* __restrict__ wwq,
    float* __restrict__ kbuf, float* __restrict__ vbuf, float* __restrict__ wqbuf) {
  int gw = (blockIdx.x * 256 + threadIdx.x) >> 6;  // 0..6143
  int lane = threadIdx.x & 63;
  int which = gw >> 11;
  int j = gw & 2047;
  const float* W = which == 0 ? wrk : (which == 1 ? wrv : wwq);
  float* O = which == 0 ? kbuf : (which == 1 ? vbuf : wqbuf);
  const f32x4* Wrow = (const f32x4*)(W + (size_t)j * D_);
  const f32x4* M4 = (const f32x4*)mem;
  float acc[8];
#pragma unroll
  for (int kk = 0; kk < 8; ++kk) acc[kk] = 0.f;
#pragma unroll
  for (int t = 0; t < 8; ++t) {
    f32x4 w4 = Wrow[lane + 64 * t];
#pragma unroll
    for (int kk = 0; kk < 8; ++kk) {
      f32x4 m4 = M4[kk * 512 + lane + 64 * t];
      acc[kk] += w4[0] * m4[0] + w4[1] * m4[1] + w4[2] * m4[2] + w4[3] * m4[3];
    }
  }
#pragma unroll
  for (int off = 1; off < 64; off <<= 1)
#pragma unroll
    for (int kk = 0; kk < 8; ++kk) acc[kk] += __shfl_xor(acc[kk], off, 64);
  if (lane == 0) {
#pragma unroll
    for (int kk = 0; kk < 8; ++kk) O[kk * D_ + j] = acc[kk];
  }
}

// ---- K2: PRT[80][2048] fp32: rows 0..63 = P (scaled 1/16), rows 64..71 = R
// Split 2x vs R8: each (ic, sub) block handles a 128-wide half of the j-range;
// both halves atomicAdd into memset-0 PRT. 256 blocks -> 1/CU.
__global__ __launch_bounds__(256) void k_pr(
    const float* __restrict__ wrq, const float* __restrict__ wwk,
    const float* __restrict__ kbuf, const float* __restrict__ wqbuf,
    float* __restrict__ PRT) {
  int b = blockIdx.x;            // 0..255 ; b = ic*16 + sub*2 + half (+128 for R)
  int tid = threadIdx.x;
  int half = b & 1;
  int sub = (b >> 1) & 7;        // h (P part) or jc (R part)
  int ic = (b >> 4) & 7;
  int i = ic * 256 + tid;
  bool isP = b < 128;
  const float* W = isP ? wrq : wwk;
  const float* V = isP ? kbuf : wqbuf;
  float scale = isP ? SCALE_R : SCALE_W;
  int rowbase = isP ? sub * 8 : 64;
  float acc[8];
#pragma unroll
  for (int kk = 0; kk < 8; ++kk) acc[kk] = 0.f;
  for (int jj = half * 128; jj < half * 128 + 128; ++jj) {
    int j = sub * 256 + jj;
    float wv = W[(size_t)j * D_ + i];
#pragma unroll
    for (int kk = 0; kk < 8; ++kk) acc[kk] += wv * V[kk * D_ + j];
  }
#pragma unroll
  for (int kk = 0; kk < 8; ++kk)
    atomicAdd(&PRT[(rowbase + kk) * D_ + i], acc[kk] * scale);
}

// ---- K_prep: fused  Wp = bf16(gamma⊙Wout row),  c1[j]=Σ gamma*W, c2[j]=Σ beta*W
__global__ __launch_bounds__(256) void k_prep(const float* __restrict__ wro,
                                              const float* __restrict__ gamma,
                                              const float* __restrict__ beta,
                                              unsigned short* __restrict__ wp,
                                              float* __restrict__ c1, float* __restrict__ c2) {
  __shared__ float red1[4], red2[4];
  int j = blockIdx.x;
  int tid = threadIdx.x;
  int d = tid * 8;
  const float* src = wro + (size_t)j * D_ + d;
  f32x4 a = *(const f32x4*)src, b = *(const f32x4*)(src + 4);
  f32x4 g0 = *(const f32x4*)(gamma + d), g1 = *(const f32x4*)(gamma + d + 4);
  f32x4 b0 = *(const f32x4*)(beta + d), b1 = *(const f32x4*)(beta + d + 4);
  ushort4 o0, o1;
  o0.x = f2bf(a[0] * g0[0]); o0.y = f2bf(a[1] * g0[1]);
  o0.z = f2bf(a[2] * g0[2]); o0.w = f2bf(a[3] * g0[3]);
  o1.x = f2bf(b[0] * g1[0]); o1.y = f2bf(b[1] * g1[1]);
  o1.z = f2bf(b[2] * g1[2]); o1.w = f2bf(b[3] * g1[3]);
  unsigned short* dst = wp + (size_t)j * D_ + d;
  *(ushort4*)dst = o0;
  *(ushort4*)(dst + 4) = o1;
  float s1 = a[0] * g0[0] + a[1] * g0[1] + a[2] * g0[2] + a[3] * g0[3] +
             b[0] * g1[0] + b[1] * g1[1] + b[2] * g1[2] + b[3] * g1[3];
  float s2 = a[0] * b0[0] + a[1] * b0[1] + a[2] * b0[2] + a[3] * b0[3] +
             b[0] * b1[0] + b[1] * b1[1] + b[2] * b1[2] + b[3] * b1[3];
#pragma unroll
  for (int off = 1; off < 64; off <<= 1) {
    s1 += __shfl_xor(s1, off, 64);
    s2 += __shfl_xor(s2, off, 64);
  }
  int wave = tid >> 6, lane = tid & 63;
  if (lane == 0) { red1[wave] = s1; red2[wave] = s2; }
  __syncthreads();
  if (tid == 0) {
    c1[j] = red1[0] + red1[1] + red1[2] + red1[3];
    c2[j] = red2[0] + red2[1] + red2[2] + red2[3];
  }
}

// ---- K3: fused MFMA S-GEMM + in-reg PER-HEAD softmax + ro + (raw ro, mu, rstd) + u-partials
__global__ __launch_bounds__(256) void k_main(
    const float* __restrict__ hidden, const float* __restrict__ PRT,
    const float* __restrict__ vbuf,
    unsigned short* __restrict__ Xhat, float* __restrict__ mu_out,
    float* __restrict__ rstd_out,
    float* __restrict__ upart, float* __restrict__ Zpart) {
  __shared__ unsigned short Ah[2][64 * 64];   // 16 KB, XOR-swizzled bf16 hidden tile
  __shared__ unsigned short Bh[2][80 * 64];   // 20 KB, XOR-swizzled bf16 PRT tile
  __shared__ unsigned short attnL[64 * 64];   // 8 KB bf16 attn
  __shared__ float e8lds[64][8];              // 2 KB
  const int tid = threadIdx.x;
  const int row0 = blockIdx.x * 64;
  const int wave = tid >> 6, lane = tid & 63;
  const int fl = lane & 15, fk = lane >> 4;
  const int ar = tid >> 2, acg = tid & 3;     // A staging: row, 16-col group

  f32x4 sA0[4], sB0[5], sA1[4], sB1[5];

  auto loadAB = [&](f32x4* a, f32x4* b, int t) {
    const float* srcA = hidden + (size_t)(row0 + ar) * D_ + t * 64 + acg * 16;
#pragma unroll
    for (int q = 0; q < 4; ++q) a[q] = *(const f32x4*)(srcA + q * 4);
#pragma unroll
    for (int p = 0; p < 5; ++p) {
      int e = p * 256 + tid;
      int rB = e >> 4, c4 = e & 15;
      b[p] = *(const f32x4*)(PRT + (size_t)rB * D_ + t * 64 + c4 * 4);
    }
  };
  auto writeAB = [&](int buf, f32x4* a, f32x4* b) {
#pragma unroll
    for (int hh = 0; hh < 2; ++hh) {
      f32x4 x = a[hh * 2], y = a[hh * 2 + 1];
      ushort4 o0 = {f2bf(x[0]), f2bf(x[1]), f2bf(x[2]), f2bf(x[3])};
      ushort4 o1 = {f2bf(y[0]), f2bf(y[1]), f2bf(y[2]), f2bf(y[3])};
      int idx = (ar * 64 + acg * 16 + hh * 8) ^ ((ar & 7) << 3);
      *(ushort4*)&Ah[buf][idx] = o0;
      *(ushort4*)&Ah[buf][idx + 4] = o1;
    }
#pragma unroll
    for (int p = 0; p < 5; ++p) {
      int e = p * 256 + tid;
      int rB = e >> 4, c4 = e & 15;
      ushort4 o = {f2bf(b[p][0]), f2bf(b[p][1]), f2bf(b[p][2]), f2bf(b[p][3])};
      int idx = (rB * 64 + c4 * 4) ^ ((rB & 7) << 3);
      *(ushort4*)&Bh[buf][idx] = o;
    }
  };

  f32x4 acc[5];
#pragma unroll
  for (int n = 0; n < 5; ++n) acc[n] = (f32x4){0.f, 0.f, 0.f, 0.f};

  auto compute = [&](int buf) {
#pragma unroll
    for (int kk = 0; kk < 2; ++kk) {
      int klo = kk * 32 + fk * 8;
      bf16x8 af = *(const bf16x8*)&Ah[buf][((wave * 16 + fl) * 64 + klo) ^ ((fl & 7) << 3)];
#pragma unroll
      for (int n = 0; n < 5; ++n) {
        bf16x8 bf = *(const bf16x8*)&Bh[buf][((n * 16 + fl) * 64 + klo) ^ ((fl & 7) << 3)];
        acc[n] = __builtin_amdgcn_mfma_f32_16x16x32_bf16(af, bf, acc[n], 0, 0, 0);
      }
    }
  };

  loadAB(sA0, sB0, 0);
  loadAB(sA1, sB1, 1);
  for (int t = 0; t < 32; t += 2) {
    writeAB(0, sA0, sB0);
    if (t + 2 < 32) loadAB(sA0, sB0, t + 2);
    __syncthreads();
    compute(0);
    writeAB(1, sA1, sB1);
    if (t + 3 < 32) loadAB(sA1, sB1, t + 3);
    __syncthreads();
    compute(1);
  }

  // ---- in-register PER-HEAD softmax.
#pragma unroll
  for (int r = 0; r < 4; ++r) {
    int rowl = wave * 16 + fk * 4 + r;
#pragma unroll
    for (int n = 0; n < 4; ++n) {
      float sv = acc[n][r];
      float m = sv;
      m = fmaxf(m, __shfl_xor(m, 1, 64));
      m = fmaxf(m, __shfl_xor(m, 2, 64));
      m = fmaxf(m, __shfl_xor(m, 4, 64));
      float e = __expf(sv - m);
      float ssum = e;
      ssum += __shfl_xor(ssum, 1, 64);
      ssum += __shfl_xor(ssum, 2, 64);
      ssum += __shfl_xor(ssum, 4, 64);
      attnL[rowl * 64 + n * 16 + fl] = f2bf(e / ssum);
    }
    if (fl < 8) e8lds[rowl][fl] = __expf(acc[4][r]);  // write-softmax numerator (|s_w|<<1)
  }
  __syncthreads();

  // ---- ro phase: per wave 16 rows; chunk c = head, d = c*256 + lane*4
  float ssum[16], ssq[16];
#pragma unroll
  for (int rw = 0; rw < 16; ++rw) { ssum[rw] = 0.f; ssq[rw] = 0.f; }
#pragma unroll
  for (int c = 0; c < 8; ++c) {
    int d0 = c * 256 + lane * 4;
    f32x4 vv[8];
#pragma unroll
    for (int kk = 0; kk < 8; ++kk) vv[kk] = *(const f32x4*)(vbuf + kk * D_ + d0);
#pragma unroll
    for (int rw = 0; rw < 16; ++rw) {
      bf16x8 at = *(const bf16x8*)&attnL[(wave * 16 + rw) * 64 + c * 8];
      f32x4 ro = (float)at[0] * vv[0] + (float)at[1] * vv[1] +
                 (float)at[2] * vv[2] + (float)at[3] * vv[3] +
                 (float)at[4] * vv[4] + (float)at[5] * vv[5] +
                 (float)at[6] * vv[6] + (float)at[7] * vv[7];
      ssum[rw] += ro[0] + ro[1] + ro[2] + ro[3];
      ssq[rw] += ro[0] * ro[0] + ro[1] * ro[1] + ro[2] * ro[2] + ro[3] * ro[3];
      ushort4 o = {f2bf(ro[0]), f2bf(ro[1]), f2bf(ro[2]), f2bf(ro[3])};
      *(ushort4*)(Xhat + (size_t)(row0 + wave * 16 + rw) * D_ + d0) = o;
    }
  }
  float muv = 0.f, rstdv = 0.f;
#pragma unroll
  for (int rw = 0; rw < 16; ++rw) {
    float s = ssum[rw], q = ssq[rw];
#pragma unroll
    for (int off = 1; off < 64; off <<= 1) {
      s += __shfl_xor(s, off, 64);
      q += __shfl_xor(q, off, 64);
    }
    float m = s * (1.f / 2048.f);
    float var = q * (1.f / 2048.f) - m * m;
    float rs = rsqrtf(var + 1e-5f);
    if (lane == rw) { muv = m; rstdv = rs; }
  }
  if (lane < 16) {
    mu_out[row0 + wave * 16 + lane] = muv;
    rstd_out[row0 + wave * 16 + lane] = rstdv;
  }
  __syncthreads();

  // ---- u-partials: wave owns 512-wide d-range, 8-row load strips
  for (int dt = 0; dt < 2; ++dt) {
    int d0 = wave * 512 + dt * 256 + lane * 4;
    f32x4 ua[8];
#pragma unroll
    for (int kk = 0; kk < 8; ++kk) ua[kk] = (f32x4){0.f, 0.f, 0.f, 0.f};
    for (int r8 = 0; r8 < 64; r8 += 8) {
      f32x4 hv[8];
#pragma unroll
      for (int q = 0; q < 8; ++q)
        hv[q] = *(const f32x4*)(hidden + (size_t)(row0 + r8 + q) * D_ + d0);
#pragma unroll
      for (int q = 0; q < 8; ++q) {
        f32x4 e0 = *(const f32x4*)&e8lds[r8 + q][0];
        f32x4 e1 = *(const f32x4*)&e8lds[r8 + q][4];
        ua[0] += e0[0] * hv[q]; ua[1] += e0[1] * hv[q];
        ua[2] += e0[2] * hv[q]; ua[3] += e0[3] * hv[q];
        ua[4] += e1[0] * hv[q]; ua[5] += e1[1] * hv[q];
        ua[6] += e1[2] * hv[q]; ua[7] += e1[3] * hv[q];
      }
    }
#pragma unroll
    for (int kk = 0; kk < 8; ++kk)
      *(f32x4*)(upart + ((size_t)blockIdx.x * 8 + kk) * D_ + d0) = ua[kk];
  }
  if (tid < 8) {
    float z = 0.f;
    for (int r = 0; r < 64; ++r) z += e8lds[r][tid];
    Zpart[blockIdx.x * 8 + tid] = z;
  }
}

// ---- K4: reduce u-partials, t = u/Z  ([8][2048])
__global__ __launch_bounds__(256) void k_ured(const float* __restrict__ upart,
                                              const float* __restrict__ Zpart,
                                              float* __restrict__ tbuf) {
  int g = blockIdx.x * 256 + threadIdx.x;  // 0..16383
  int kk = g >> 11, d = g & 2047;
  float z = 0.f;
  for (int b = 0; b < 256; ++b) z += Zpart[b * 8 + kk];
  float u = 0.f;
  for (int b = 0; b < 256; ++b) u += upart[((size_t)b * 8 + kk) * 2048 + d];
  tbuf[g] = u / z;
}

// ---- K5b: new_memory = (1-wg)*memory + wg * (t @ Wwv.T)
__global__ __launch_bounds__(256) void k_newmem(
    const float* __restrict__ tbuf, const float* __restrict__ wwv,
    const float* __restrict__ mem, const float* __restrict__ wgate,
    float* __restrict__ out_mem) {
  int j = (blockIdx.x * 256 + threadIdx.x) >> 6;  // 0..2047
  int lane = threadIdx.x & 63;
  const f32x4* Wrow = (const f32x4*)(wwv + (size_t)j * D_);
  const f32x4* T4 = (const f32x4*)tbuf;
  float acc[8];
#pragma unroll
  for (int kk = 0; kk < 8; ++kk) acc[kk] = 0.f;
#pragma unroll
  for (int t = 0; t < 8; ++t) {
    f32x4 w4 = Wrow[lane + 64 * t];
#pragma unroll
    for (int kk = 0; kk < 8; ++kk) {
      f32x4 t4 = T4[kk * 512 + lane + 64 * t];
      acc[kk] += w4[0] * t4[0] + w4[1] * t4[1] + w4[2] * t4[2] + w4[3] * t4[3];
    }
  }
#pragma unroll
  for (int off = 1; off < 64; off <<= 1)
#pragma unroll
    for (int kk = 0; kk < 8; ++kk) acc[kk] += __shfl_xor(acc[kk], off, 64);
  if (lane == 0) {
    float wg = 1.f / (1.f + __expf(-wgate[0]));
#pragma unroll
    for (int kk = 0; kk < 8; ++kk)
      out_mem[kk * D_ + j] = (1.f - wg) * mem[kk * D_ + j] + wg * acc[kk];
  }
}

// ---- K5: result = hidden + g*(rstd*(ro@W'^T) - rstd*mu*c1 + c2)
// R4-locked structure (best measured: 263us, MfmaUtil 22%, 0 bank conflicts):
// 128x128, BK=64, dbuf 64 KB, __syncthreads-drain per tile, identity block
// map (bn%8 per XCD -> B L2-resident). R5-R9 schedule variants (counted
// vmcnt, triple-buffer, single-buffer hi-occ, 8-phase) all landed 17-22%
// MfmaUtil — the fine interleave is not reproducible at this source level.
// New vs R4: epilogue n-innermost so each row's four 64B segments coalesce.
__global__ __launch_bounds__(256) void k_gemm(
    const unsigned short* __restrict__ A,  // raw ro bf16 [16384][2048]
    const unsigned short* __restrict__ B,  // W' bf16 [2048][2048] (row j = out col)
    const float* __restrict__ hidden, const float* __restrict__ gate,
    const float* __restrict__ mu, const float* __restrict__ rstd,
    const float* __restrict__ c1, const float* __restrict__ c2,
    float* __restrict__ out) {
  __shared__ unsigned short As[2][128 * 64];
  __shared__ unsigned short Bs[2][128 * 64];
  const int tid = threadIdx.x;
  const int bm = blockIdx.x >> 4, bn = blockIdx.x & 15;
  const int row0 = bm * 128, col0 = bn * 128;
  const int wave = tid >> 6, lane = tid & 63;
  const int wr = wave >> 1, wc = wave & 1;
  const int fl = lane & 15, fk = lane >> 4;
  const int srow = tid >> 3;
  const int scol_l = (tid & 7) * 8;                 // linear LDS dest col
  const int scol_g = ((tid & 7) ^ (srow & 7)) * 8;  // pre-swizzled global col

  f32x4 acc[4][4];
#pragma unroll
  for (int m = 0; m < 4; ++m)
#pragma unroll
    for (int n = 0; n < 4; ++n) acc[m][n] = (f32x4){0.f, 0.f, 0.f, 0.f};

  auto stage = [&](int buf, int kt) {
    const int k0 = kt * 64;
#pragma unroll
    for (int p = 0; p < 4; ++p) {
      int r = srow + p * 32;  // (r&7) == (srow&7)
      lds_load16(&As[buf][r * 64 + scol_l], A + (size_t)(row0 + r) * D_ + k0 + scol_g);
      lds_load16(&Bs[buf][r * 64 + scol_l], B + (size_t)(col0 + r) * D_ + k0 + scol_g);
    }
  };

  stage(0, 0);
  for (int kt = 0; kt < 32; ++kt) {
    __syncthreads();  // stage(kt) complete (drains vmcnt)
    if (kt + 1 < 32) stage((kt + 1) & 1, kt + 1);
    const int cb = kt & 1;
#pragma unroll
    for (int kkk = 0; kkk < 2; ++kkk) {
      const int gsw = ((kkk * 4 + fk) ^ (fl & 7)) * 8;
      bf16x8 af[4], bfr[4];
#pragma unroll
      for (int m = 0; m < 4; ++m)
        af[m] = *(const bf16x8*)&As[cb][(wr * 64 + m * 16 + fl) * 64 + gsw];
#pragma unroll
      for (int n = 0; n < 4; ++n)
        bfr[n] = *(const bf16x8*)&Bs[cb][(wc * 64 + n * 16 + fl) * 64 + gsw];
#pragma unroll
      for (int m = 0; m < 4; ++m)
#pragma unroll
        for (int n = 0; n < 4; ++n)
          acc[m][n] = __builtin_amdgcn_mfma_f32_16x16x32_bf16(af[m], bfr[n], acc[m][n], 0, 0, 0);
    }
  }
  float g = 1.f / (1.f + __expf(-gate[0]));
  int cols[4];
  float C1v[4], C2v[4];
#pragma unroll
  for (int n = 0; n < 4; ++n) {
    cols[n] = col0 + wc * 64 + n * 16 + fl;
    C1v[n] = c1[cols[n]] * g;
    C2v[n] = c2[cols[n]] * g;
  }
#pragma unroll
  for (int m = 0; m < 4; ++m)
#pragma unroll
    for (int r = 0; r < 4; ++r) {
      int row = row0 + wr * 64 + m * 16 + fk * 4 + r;
      float RS = rstd[row], MU = mu[row];
      const float* hrow = hidden + (size_t)row * D_;
      float* orow = out + (size_t)row * D_;
#pragma unroll
      for (int n = 0; n < 4; ++n)
        orow[cols[n]] = hrow[cols[n]] + g * RS * acc[m][n][r] - RS * MU * C1v[n] + C2v[n];
    }
}

extern "C" void kernel_launch(void* const* d_in, const int* in_sizes, int n_in,
                              void* d_out, int out_size, void* d_ws, size_t ws_size,
                              hipStream_t stream) {
  const float* hidden = (const float*)d_in[0];
  const float* mem    = (const float*)d_in[1];
  const float* wrq = (const float*)d_in[2];
  const float* wrk = (const float*)d_in[3];
  const float* wrv = (const float*)d_in[4];
  const float* wro = (const float*)d_in[5];
  const float* wwq = (const float*)d_in[6];
  const float* wwk = (const float*)d_in[7];
  const float* wwv = (const float*)d_in[8];
  const float* gamma = (const float*)d_in[9];
  const float* beta  = (const float*)d_in[10];
  const float* gate  = (const float*)d_in[11];
  const float* wgate = (const float*)d_in[12];
  float* out = (float*)d_out;

  char* ws = (char*)d_ws;
  float* kbuf  = (float*)(ws);                    // 64 KB; reused as mu after k_pr
  float* vbuf  = (float*)(ws + (64 << 10));       // 64 KB
  float* wqbuf = (float*)(ws + (128 << 10));      // 64 KB; reused as rstd after k_pr
  float* PRT   = (float*)(ws + (192 << 10));      // 640 KB fp32
  float* tbuf  = (float*)(ws + (832 << 10));      // 64 KB
  float* Zpart = (float*)(ws + (896 << 10));      // 8 KB
  float* c1    = (float*)(ws + (904 << 10));      // 8 KB
  float* c2    = (float*)(ws + (912 << 10));      // 8 KB
  float* upart = (float*)(ws + (960ull << 10));   // 16 MB
  unsigned short* Wp   = (unsigned short*)(ws + (960ull << 10) + (16ull << 20));  // 8 MB
  unsigned short* Xhat = (unsigned short*)(ws + (960ull << 10) + (24ull << 20));  // 64 MB
  float* mu   = kbuf;    // overlay: kbuf dead after k_pr
  float* rstd = wqbuf;   // overlay: wqbuf dead after k_pr

  hipMemsetAsync(PRT, 0, 80 * 2048 * sizeof(float), stream);
  k_prep<<<2048, 256, 0, stream>>>(wro, gamma, beta, Wp, c1, c2);
  k_kvwq<<<1536, 256, 0, stream>>>(mem, wrk, wrv, wwq, kbuf, vbuf, wqbuf);
  k_pr<<<256, 256, 0, stream>>>(wrq, wwk, kbuf, wqbuf, PRT);
  k_main<<<256, 256, 0, stream>>>(hidden, PRT, vbuf, Xhat, mu, rstd, upart, Zpart);
  k_ured<<<64, 256, 0, stream>>>(upart, Zpart, tbuf);
  k_newmem<<<512, 256, 0, stream>>>(tbuf, wwv, mem, wgate, out + (size_t)N_ * D_);
  k_gemm<<<2048, 256, 0, stream>>>(Xhat, Wp, hidden, gate, mu, rstd, c1, c2, out);
}

// Round 11
// 333.739 us; speedup vs baseline: 1.5500x; 1.0285x over previous
//
#include <hip/hip_runtime.h>
#include <hip/hip_bf16.h>
#include <stdint.h>

static constexpr int N_ = 16384;
static constexpr int D_ = 2048;
static constexpr float SCALE_R = 1.0f / 16.0f;            // 1/sqrt(HD=256)
static constexpr float SCALE_W = 0.02209708691207961f;    // 1/sqrt(D=2048)

typedef __bf16 bf16x8 __attribute__((ext_vector_type(8)));
typedef float f32x4 __attribute__((ext_vector_type(4)));

__device__ __forceinline__ unsigned short f2bf(float f) {
  unsigned int u = __float_as_uint(f);
  unsigned int r = (u + 0x7fff + ((u >> 16) & 1)) >> 16;  // RNE
  return (unsigned short)r;
}

__device__ __forceinline__ void lds_load16(void* lds, const void* g) {
  __builtin_amdgcn_global_load_lds(
      (const __attribute__((address_space(1))) uint32_t*)(uintptr_t)g,
      (__attribute__((address_space(3))) uint32_t*)(uint32_t)(uintptr_t)lds,
      16, 0, 0);
}

// ---- K1: k = memory@Wrk.T, v = memory@Wrv.T, wq = memory@Wwq.T  (each [8][2048])
__global__ __launch_bounds__(256) void k_kvwq(
    const float* __restrict__ mem, const float* __restrict__ wrk,
    const float* __restrict__ wrv, const float* __restrict__ wwq,
    float* __restrict__ kbuf, float* __restrict__ vbuf, float* __restrict__ wqbuf) {
  int gw = (blockIdx.x * 256 + threadIdx.x) >> 6;  // 0..6143
  int lane = threadIdx.x & 63;
  int which = gw >> 11;
  int j = gw & 2047;
  const float* W = which == 0 ? wrk : (which == 1 ? wrv : wwq);
  float* O = which == 0 ? kbuf : (which == 1 ? vbuf : wqbuf);
  const f32x4* Wrow = (const f32x4*)(W + (size_t)j * D_);
  const f32x4* M4 = (const f32x4*)mem;
  float acc[8];
#pragma unroll
  for (int kk = 0; kk < 8; ++kk) acc[kk] = 0.f;
#pragma unroll
  for (int t = 0; t < 8; ++t) {
    f32x4 w4 = Wrow[lane + 64 * t];
#pragma unroll
    for (int kk = 0; kk < 8; ++kk) {
      f32x4 m4 = M4[kk * 512 + lane + 64 * t];
      acc[kk] += w4[0] * m4[0] + w4[1] * m4[1] + w4[2] * m4[2] + w4[3] * m4[3];
    }
  }
#pragma unroll
  for (int off = 1; off < 64; off <<= 1)
#pragma unroll
    for (int kk = 0; kk < 8; ++kk) acc[kk] += __shfl_xor(acc[kk], off, 64);
  if (lane == 0) {
#pragma unroll
    for (int kk = 0; kk < 8; ++kk) O[kk * D_ + j] = acc[kk];
  }
}

// ---- K2: PRT[80][2048] fp32 via atomics. 4-way j-split: 512 blocks (1024 waves),
// quarter-length (64-iter) chains, unrolled.
__global__ __launch_bounds__(256) void k_pr(
    const float* __restrict__ wrq, const float* __restrict__ wwk,
    const float* __restrict__ kbuf, const float* __restrict__ wqbuf,
    float* __restrict__ PRT) {
  int b = blockIdx.x;            // 0..511
  int tid = threadIdx.x;
  bool isP = b < 256;
  int bb = isP ? b : b - 256;
  int q = bb & 3;                // j quarter
  int sub = (bb >> 2) & 7;       // h (P) or jc (R)
  int ic = bb >> 5;
  int i = ic * 256 + tid;
  const float* W = isP ? wrq : wwk;
  const float* V = isP ? kbuf : wqbuf;
  float scale = isP ? SCALE_R : SCALE_W;
  int rowbase = isP ? sub * 8 : 64;
  float acc[8];
#pragma unroll
  for (int kk = 0; kk < 8; ++kk) acc[kk] = 0.f;
  int j0 = sub * 256 + q * 64;
#pragma unroll 4
  for (int jj = 0; jj < 64; ++jj) {
    int j = j0 + jj;
    float wv = W[(size_t)j * D_ + i];
#pragma unroll
    for (int kk = 0; kk < 8; ++kk) acc[kk] += wv * V[kk * D_ + j];
  }
#pragma unroll
  for (int kk = 0; kk < 8; ++kk)
    atomicAdd(&PRT[(rowbase + kk) * D_ + i], acc[kk] * scale);
}

// ---- convert PRT fp32 -> PRTb bf16 (after all k_pr atomics)
__global__ __launch_bounds__(256) void k_prtb(const float* __restrict__ PRT,
                                              unsigned short* __restrict__ PRTb) {
  int i = (blockIdx.x * 256 + threadIdx.x) * 4;
  f32x4 v = *(const f32x4*)(PRT + i);
  ushort4 o = {f2bf(v[0]), f2bf(v[1]), f2bf(v[2]), f2bf(v[3])};
  *(ushort4*)(PRTb + i) = o;
}

// ---- K_prep: fused  Wp = bf16(gamma⊙Wout row),  c1[j]=Σ gamma*W, c2[j]=Σ beta*W
__global__ __launch_bounds__(256) void k_prep(const float* __restrict__ wro,
                                              const float* __restrict__ gamma,
                                              const float* __restrict__ beta,
                                              unsigned short* __restrict__ wp,
                                              float* __restrict__ c1, float* __restrict__ c2) {
  __shared__ float red1[4], red2[4];
  int j = blockIdx.x;
  int tid = threadIdx.x;
  int d = tid * 8;
  const float* src = wro + (size_t)j * D_ + d;
  f32x4 a = *(const f32x4*)src, b = *(const f32x4*)(src + 4);
  f32x4 g0 = *(const f32x4*)(gamma + d), g1 = *(const f32x4*)(gamma + d + 4);
  f32x4 b0 = *(const f32x4*)(beta + d), b1 = *(const f32x4*)(beta + d + 4);
  ushort4 o0, o1;
  o0.x = f2bf(a[0] * g0[0]); o0.y = f2bf(a[1] * g0[1]);
  o0.z = f2bf(a[2] * g0[2]); o0.w = f2bf(a[3] * g0[3]);
  o1.x = f2bf(b[0] * g1[0]); o1.y = f2bf(b[1] * g1[1]);
  o1.z = f2bf(b[2] * g1[2]); o1.w = f2bf(b[3] * g1[3]);
  unsigned short* dst = wp + (size_t)j * D_ + d;
  *(ushort4*)dst = o0;
  *(ushort4*)(dst + 4) = o1;
  float s1 = a[0] * g0[0] + a[1] * g0[1] + a[2] * g0[2] + a[3] * g0[3] +
             b[0] * g1[0] + b[1] * g1[1] + b[2] * g1[2] + b[3] * g1[3];
  float s2 = a[0] * b0[0] + a[1] * b0[1] + a[2] * b0[2] + a[3] * b0[3] +
             b[0] * b1[0] + b[1] * b1[1] + b[2] * b1[2] + b[3] * b1[3];
#pragma unroll
  for (int off = 1; off < 64; off <<= 1) {
    s1 += __shfl_xor(s1, off, 64);
    s2 += __shfl_xor(s2, off, 64);
  }
  int wave = tid >> 6, lane = tid & 63;
  if (lane == 0) { red1[wave] = s1; red2[wave] = s2; }
  __syncthreads();
  if (tid == 0) {
    c1[j] = red1[0] + red1[1] + red1[2] + red1[3];
    c2[j] = red2[0] + red2[1] + red2[2] + red2[3];
  }
}

// ---- K3: fused MFMA S-GEMM + in-reg PER-HEAD softmax + ro + (raw ro, mu, rstd) + u-partials
// B (PRTb bf16) now staged via global_load_lds (pre-swizzled source, linear
// dest) — removes per-tile B loads/cvt/ds_writes. A stays reg-staged (fp32->bf16).
__global__ __launch_bounds__(256) void k_main(
    const float* __restrict__ hidden, const unsigned short* __restrict__ PRTb,
    const float* __restrict__ vbuf,
    unsigned short* __restrict__ Xhat, float* __restrict__ mu_out,
    float* __restrict__ rstd_out,
    float* __restrict__ upart, float* __restrict__ Zpart) {
  __shared__ unsigned short Ah[2][64 * 64];   // 16 KB, XOR-swizzled bf16 hidden tile
  __shared__ unsigned short Bh[2][80 * 64];   // 20 KB, XOR-swizzled bf16 PRT tile
  __shared__ unsigned short attnL[64 * 64];   // 8 KB bf16 attn
  __shared__ float e8lds[64][8];              // 2 KB
  const int tid = threadIdx.x;
  const int row0 = blockIdx.x * 64;
  const int wave = tid >> 6, lane = tid & 63;
  const int fl = lane & 15, fk = lane >> 4;
  const int ar = tid >> 2, acg = tid & 3;     // A staging: row, 16-col group

  f32x4 sA0[4], sA1[4];

  auto loadA = [&](f32x4* a, int t) {
    const float* srcA = hidden + (size_t)(row0 + ar) * D_ + t * 64 + acg * 16;
#pragma unroll
    for (int q = 0; q < 4; ++q) a[q] = *(const f32x4*)(srcA + q * 4);
  };
  auto writeA = [&](int buf, f32x4* a) {
#pragma unroll
    for (int hh = 0; hh < 2; ++hh) {
      f32x4 x = a[hh * 2], y = a[hh * 2 + 1];
      ushort4 o0 = {f2bf(x[0]), f2bf(x[1]), f2bf(x[2]), f2bf(x[3])};
      ushort4 o1 = {f2bf(y[0]), f2bf(y[1]), f2bf(y[2]), f2bf(y[3])};
      int idx = (ar * 64 + acg * 16 + hh * 8) ^ ((ar & 7) << 3);
      *(ushort4*)&Ah[buf][idx] = o0;
      *(ushort4*)&Ah[buf][idx + 4] = o1;
    }
  };
  auto stageB = [&](int buf, int kt) {  // 640 x 16B granules over [80][64] bf16
#pragma unroll
    for (int s = 0; s < 2; ++s) {
      int e = s * 256 + tid;
      int rB = e >> 3, gl = e & 7, gs = gl ^ (rB & 7);
      lds_load16(&Bh[buf][rB * 64 + gl * 8],
                 PRTb + (size_t)rB * D_ + kt * 64 + gs * 8);
    }
    if (tid < 128) {
      int e = 512 + tid;
      int rB = e >> 3, gl = e & 7, gs = gl ^ (rB & 7);
      lds_load16(&Bh[buf][rB * 64 + gl * 8],
                 PRTb + (size_t)rB * D_ + kt * 64 + gs * 8);
    }
  };

  f32x4 acc[5];
#pragma unroll
  for (int n = 0; n < 5; ++n) acc[n] = (f32x4){0.f, 0.f, 0.f, 0.f};

  auto compute = [&](int buf) {
#pragma unroll
    for (int kk = 0; kk < 2; ++kk) {
      int klo = kk * 32 + fk * 8;
      bf16x8 af = *(const bf16x8*)&Ah[buf][((wave * 16 + fl) * 64 + klo) ^ ((fl & 7) << 3)];
#pragma unroll
      for (int n = 0; n < 5; ++n) {
        bf16x8 bf = *(const bf16x8*)&Bh[buf][((n * 16 + fl) * 64 + klo) ^ ((fl & 7) << 3)];
        acc[n] = __builtin_amdgcn_mfma_f32_16x16x32_bf16(af, bf, acc[n], 0, 0, 0);
      }
    }
  };

  loadA(sA0, 0);
  loadA(sA1, 1);
  stageB(0, 0);
  for (int t = 0; t < 32; t += 2) {
    writeA(0, sA0);
    if (t + 2 < 32) loadA(sA0, t + 2);
    __syncthreads();          // (a): Ah0+Bh0(t) ready; all waves done reading Bh1(t-1)
    stageB(1, t + 1);         // t+1 <= 31 always
    compute(0);               // tile t
    writeA(1, sA1);
    if (t + 3 < 32) loadA(sA1, t + 3);
    __syncthreads();          // (b): Ah1+Bh1(t+1) ready; all waves done reading Bh0(t)
    if (t + 2 < 32) stageB(0, t + 2);
    compute(1);               // tile t+1
  }

  // ---- in-register PER-HEAD softmax.
#pragma unroll
  for (int r = 0; r < 4; ++r) {
    int rowl = wave * 16 + fk * 4 + r;
#pragma unroll
    for (int n = 0; n < 4; ++n) {
      float sv = acc[n][r];
      float m = sv;
      m = fmaxf(m, __shfl_xor(m, 1, 64));
      m = fmaxf(m, __shfl_xor(m, 2, 64));
      m = fmaxf(m, __shfl_xor(m, 4, 64));
      float e = __expf(sv - m);
      float ssum = e;
      ssum += __shfl_xor(ssum, 1, 64);
      ssum += __shfl_xor(ssum, 2, 64);
      ssum += __shfl_xor(ssum, 4, 64);
      attnL[rowl * 64 + n * 16 + fl] = f2bf(e / ssum);
    }
    if (fl < 8) e8lds[rowl][fl] = __expf(acc[4][r]);  // write-softmax numerator (|s_w|<<1)
  }
  __syncthreads();

  // ---- ro phase: per wave 16 rows; chunk c = head, d = c*256 + lane*4
  float ssum[16], ssq[16];
#pragma unroll
  for (int rw = 0; rw < 16; ++rw) { ssum[rw] = 0.f; ssq[rw] = 0.f; }
#pragma unroll
  for (int c = 0; c < 8; ++c) {
    int d0 = c * 256 + lane * 4;
    f32x4 vv[8];
#pragma unroll
    for (int kk = 0; kk < 8; ++kk) vv[kk] = *(const f32x4*)(vbuf + kk * D_ + d0);
#pragma unroll
    for (int rw = 0; rw < 16; ++rw) {
      bf16x8 at = *(const bf16x8*)&attnL[(wave * 16 + rw) * 64 + c * 8];
      f32x4 ro = (float)at[0] * vv[0] + (float)at[1] * vv[1] +
                 (float)at[2] * vv[2] + (float)at[3] * vv[3] +
                 (float)at[4] * vv[4] + (float)at[5] * vv[5] +
                 (float)at[6] * vv[6] + (float)at[7] * vv[7];
      ssum[rw] += ro[0] + ro[1] + ro[2] + ro[3];
      ssq[rw] += ro[0] * ro[0] + ro[1] * ro[1] + ro[2] * ro[2] + ro[3] * ro[3];
      ushort4 o = {f2bf(ro[0]), f2bf(ro[1]), f2bf(ro[2]), f2bf(ro[3])};
      *(ushort4*)(Xhat + (size_t)(row0 + wave * 16 + rw) * D_ + d0) = o;
    }
  }
  float muv = 0.f, rstdv = 0.f;
#pragma unroll
  for (int rw = 0; rw < 16; ++rw) {
    float s = ssum[rw], q = ssq[rw];
#pragma unroll
    for (int off = 1; off < 64; off <<= 1) {
      s += __shfl_xor(s, off, 64);
      q += __shfl_xor(q, off, 64);
    }
    float m = s * (1.f / 2048.f);
    float var = q * (1.f / 2048.f) - m * m;
    float rs = rsqrtf(var + 1e-5f);
    if (lane == rw) { muv = m; rstdv = rs; }
  }
  if (lane < 16) {
    mu_out[row0 + wave * 16 + lane] = muv;
    rstd_out[row0 + wave * 16 + lane] = rstdv;
  }
  __syncthreads();

  // ---- u-partials: wave owns 512-wide d-range, 8-row load strips
  for (int dt = 0; dt < 2; ++dt) {
    int d0 = wave * 512 + dt * 256 + lane * 4;
    f32x4 ua[8];
#pragma unroll
    for (int kk = 0; kk < 8; ++kk) ua[kk] = (f32x4){0.f, 0.f, 0.f, 0.f};
    for (int r8 = 0; r8 < 64; r8 += 8) {
      f32x4 hv[8];
#pragma unroll
      for (int q = 0; q < 8; ++q)
        hv[q] = *(const f32x4*)(hidden + (size_t)(row0 + r8 + q) * D_ + d0);
#pragma unroll
      for (int q = 0; q < 8; ++q) {
        f32x4 e0 = *(const f32x4*)&e8lds[r8 + q][0];
        f32x4 e1 = *(const f32x4*)&e8lds[r8 + q][4];
        ua[0] += e0[0] * hv[q]; ua[1] += e0[1] * hv[q];
        ua[2] += e0[2] * hv[q]; ua[3] += e0[3] * hv[q];
        ua[4] += e1[0] * hv[q]; ua[5] += e1[1] * hv[q];
        ua[6] += e1[2] * hv[q]; ua[7] += e1[3] * hv[q];
      }
    }
#pragma unroll
    for (int kk = 0; kk < 8; ++kk)
      *(f32x4*)(upart + ((size_t)blockIdx.x * 8 + kk) * D_ + d0) = ua[kk];
  }
  if (tid < 8) {
    float z = 0.f;
    for (int r = 0; r < 64; ++r) z += e8lds[r][tid];
    Zpart[blockIdx.x * 8 + tid] = z;
  }
}

// ---- K4: reduce u-partials, t = u/Z. 256 blocks, 4 threads/output, LDS combine.
__global__ __launch_bounds__(256) void k_ured(const float* __restrict__ upart,
                                              const float* __restrict__ Zpart,
                                              float* __restrict__ tbuf) {
  __shared__ float us[256], zs[256];
  int tid = threadIdx.x;
  int q = tid >> 6;                       // partial quarter 0..3
  int o = blockIdx.x * 64 + (tid & 63);   // output 0..16383
  int kk = o >> 11, d = o & 2047;
  float z = 0.f, u = 0.f;
#pragma unroll 4
  for (int b = q * 64; b < q * 64 + 64; ++b) {
    z += Zpart[b * 8 + kk];
    u += upart[((size_t)b * 8 + kk) * 2048 + d];
  }
  us[tid] = u; zs[tid] = z;
  __syncthreads();
  if (q == 0) {
    u += us[tid + 64] + us[tid + 128] + us[tid + 192];
    z += zs[tid + 64] + zs[tid + 128] + zs[tid + 192];
    tbuf[o] = u / z;
  }
}

// ---- K5b: new_memory = (1-wg)*memory + wg * (t @ Wwv.T)
__global__ __launch_bounds__(256) void k_newmem(
    const float* __restrict__ tbuf, const float* __restrict__ wwv,
    const float* __restrict__ mem, const float* __restrict__ wgate,
    float* __restrict__ out_mem) {
  int j = (blockIdx.x * 256 + threadIdx.x) >> 6;  // 0..2047
  int lane = threadIdx.x & 63;
  const f32x4* Wrow = (const f32x4*)(wwv + (size_t)j * D_);
  const f32x4* T4 = (const f32x4*)tbuf;
  float acc[8];
#pragma unroll
  for (int kk = 0; kk < 8; ++kk) acc[kk] = 0.f;
#pragma unroll
  for (int t = 0; t < 8; ++t) {
    f32x4 w4 = Wrow[lane + 64 * t];
#pragma unroll
    for (int kk = 0; kk < 8; ++kk) {
      f32x4 t4 = T4[kk * 512 + lane + 64 * t];
      acc[kk] += w4[0] * t4[0] + w4[1] * t4[1] + w4[2] * t4[2] + w4[3] * t4[3];
    }
  }
#pragma unroll
  for (int off = 1; off < 64; off <<= 1)
#pragma unroll
    for (int kk = 0; kk < 8; ++kk) acc[kk] += __shfl_xor(acc[kk], off, 64);
  if (lane == 0) {
    float wg = 1.f / (1.f + __expf(-wgate[0]));
#pragma unroll
    for (int kk = 0; kk < 8; ++kk)
      out_mem[kk * D_ + j] = (1.f - wg) * mem[kk * D_ + j] + wg * acc[kk];
  }
}

// ---- K5: result = hidden + g*(rstd*(ro@W'^T) - rstd*mu*c1 + c2)
// R10-locked (183us, MfmaUtil 32.5%, 0 conflicts): 128x128, BK=64, dbuf,
// __syncthreads drain, identity block map, n-innermost coalesced epilogue.
__global__ __launch_bounds__(256) void k_gemm(
    const unsigned short* __restrict__ A,  // raw ro bf16 [16384][2048]
    const unsigned short* __restrict__ B,  // W' bf16 [2048][2048] (row j = out col)
    const float* __restrict__ hidden, const float* __restrict__ gate,
    const float* __restrict__ mu, const float* __restrict__ rstd,
    const float* __restrict__ c1, const float* __restrict__ c2,
    float* __restrict__ out) {
  __shared__ unsigned short As[2][128 * 64];
  __shared__ unsigned short Bs[2][128 * 64];
  const int tid = threadIdx.x;
  const int bm = blockIdx.x >> 4, bn = blockIdx.x & 15;
  const int row0 = bm * 128, col0 = bn * 128;
  const int wave = tid >> 6, lane = tid & 63;
  const int wr = wave >> 1, wc = wave & 1;
  const int fl = lane & 15, fk = lane >> 4;
  const int srow = tid >> 3;
  const int scol_l = (tid & 7) * 8;                 // linear LDS dest col
  const int scol_g = ((tid & 7) ^ (srow & 7)) * 8;  // pre-swizzled global col

  f32x4 acc[4][4];
#pragma unroll
  for (int m = 0; m < 4; ++m)
#pragma unroll
    for (int n = 0; n < 4; ++n) acc[m][n] = (f32x4){0.f, 0.f, 0.f, 0.f};

  auto stage = [&](int buf, int kt) {
    const int k0 = kt * 64;
#pragma unroll
    for (int p = 0; p < 4; ++p) {
      int r = srow + p * 32;  // (r&7) == (srow&7)
      lds_load16(&As[buf][r * 64 + scol_l], A + (size_t)(row0 + r) * D_ + k0 + scol_g);
      lds_load16(&Bs[buf][r * 64 + scol_l], B + (size_t)(col0 + r) * D_ + k0 + scol_g);
    }
  };

  stage(0, 0);
  for (int kt = 0; kt < 32; ++kt) {
    __syncthreads();  // stage(kt) complete (drains vmcnt)
    if (kt + 1 < 32) stage((kt + 1) & 1, kt + 1);
    const int cb = kt & 1;
#pragma unroll
    for (int kkk = 0; kkk < 2; ++kkk) {
      const int gsw = ((kkk * 4 + fk) ^ (fl & 7)) * 8;
      bf16x8 af[4], bfr[4];
#pragma unroll
      for (int m = 0; m < 4; ++m)
        af[m] = *(const bf16x8*)&As[cb][(wr * 64 + m * 16 + fl) * 64 + gsw];
#pragma unroll
      for (int n = 0; n < 4; ++n)
        bfr[n] = *(const bf16x8*)&Bs[cb][(wc * 64 + n * 16 + fl) * 64 + gsw];
#pragma unroll
      for (int m = 0; m < 4; ++m)
#pragma unroll
        for (int n = 0; n < 4; ++n)
          acc[m][n] = __builtin_amdgcn_mfma_f32_16x16x32_bf16(af[m], bfr[n], acc[m][n], 0, 0, 0);
    }
  }
  float g = 1.f / (1.f + __expf(-gate[0]));
  int cols[4];
  float C1v[4], C2v[4];
#pragma unroll
  for (int n = 0; n < 4; ++n) {
    cols[n] = col0 + wc * 64 + n * 16 + fl;
    C1v[n] = c1[cols[n]] * g;
    C2v[n] = c2[cols[n]] * g;
  }
#pragma unroll
  for (int m = 0; m < 4; ++m)
#pragma unroll
    for (int r = 0; r < 4; ++r) {
      int row = row0 + wr * 64 + m * 16 + fk * 4 + r;
      float RS = rstd[row], MU = mu[row];
      const float* hrow = hidden + (size_t)row * D_;
      float* orow = out + (size_t)row * D_;
#pragma unroll
      for (int n = 0; n < 4; ++n)
        orow[cols[n]] = hrow[cols[n]] + g * RS * acc[m][n][r] - RS * MU * C1v[n] + C2v[n];
    }
}

extern "C" void kernel_launch(void* const* d_in, const int* in_sizes, int n_in,
                              void* d_out, int out_size, void* d_ws, size_t ws_size,
                              hipStream_t stream) {
  const float* hidden = (const float*)d_in[0];
  const float* mem    = (const float*)d_in[1];
  const float* wrq = (const float*)d_in[2];
  const float* wrk = (const float*)d_in[3];
  const float* wrv = (const float*)d_in[4];
  const float* wro = (const float*)d_in[5];
  const float* wwq = (const float*)d_in[6];
  const float* wwk = (const float*)d_in[7];
  const float* wwv = (const float*)d_in[8];
  const float* gamma = (const float*)d_in[9];
  const float* beta  = (const float*)d_in[10];
  const float* gate  = (const float*)d_in[11];
  const float* wgate = (const float*)d_in[12];
  float* out = (float*)d_out;

  char* ws = (char*)d_ws;
  float* kbuf  = (float*)(ws);                    // 64 KB; reused as mu after k_pr
  float* vbuf  = (float*)(ws + (64 << 10));       // 64 KB
  float* wqbuf = (float*)(ws + (128 << 10));      // 64 KB; reused as rstd after k_pr
  float* PRT   = (float*)(ws + (192 << 10));      // 640 KB fp32
  float* tbuf  = (float*)(ws + (832 << 10));      // 64 KB
  float* Zpart = (float*)(ws + (896 << 10));      // 8 KB
  float* c1    = (float*)(ws + (904 << 10));      // 8 KB
  float* c2    = (float*)(ws + (912 << 10));      // 8 KB
  unsigned short* PRTb = (unsigned short*)(ws + (960 << 10));  // 320 KB bf16
  float* upart = (float*)(ws + (1536ull << 10));  // 16 MB
  unsigned short* Wp   = (unsigned short*)(ws + (1536ull << 10) + (16ull << 20));  // 8 MB
  unsigned short* Xhat = (unsigned short*)(ws + (1536ull << 10) + (24ull << 20));  // 64 MB
  float* mu   = kbuf;    // overlay: kbuf dead after k_pr
  float* rstd = wqbuf;   // overlay: wqbuf dead after k_pr

  hipMemsetAsync(PRT, 0, 80 * 2048 * sizeof(float), stream);
  k_prep<<<2048, 256, 0, stream>>>(wro, gamma, beta, Wp, c1, c2);
  k_kvwq<<<1536, 256, 0, stream>>>(mem, wrk, wrv, wwq, kbuf, vbuf, wqbuf);
  k_pr<<<512, 256, 0, stream>>>(wrq, wwk, kbuf, wqbuf, PRT);
  k_prtb<<<160, 256, 0, stream>>>(PRT, PRTb);
  k_main<<<256, 256, 0, stream>>>(hidden, PRTb, vbuf, Xhat, mu, rstd, upart, Zpart);
  k_ured<<<256, 256, 0, stream>>>(upart, Zpart, tbuf);
  k_newmem<<<512, 256, 0, stream>>>(tbuf, wwv, mem, wgate, out + (size_t)N_ * D_);
  k_gemm<<<2048, 256, 0, stream>>>(Xhat, Wp, hidden, gate, mu, rstd, c1, c2, out);
}

// Round 12
// 322.831 us; speedup vs baseline: 1.6024x; 1.0338x over previous
//
#include <hip/hip_runtime.h>
#include <hip/hip_bf16.h>
#include <stdint.h>

static constexpr int N_ = 16384;
static constexpr int D_ = 2048;
static constexpr float SCALE_R = 1.0f / 16.0f;            // 1/sqrt(HD=256)
static constexpr float SCALE_W = 0.02209708691207961f;    // 1/sqrt(D=2048)

typedef __bf16 bf16x8 __attribute__((ext_vector_type(8)));
typedef float f32x4 __attribute__((ext_vector_type(4)));

__device__ __forceinline__ unsigned short f2bf(float f) {
  unsigned int u = __float_as_uint(f);
  unsigned int r = (u + 0x7fff + ((u >> 16) & 1)) >> 16;  // RNE
  return (unsigned short)r;
}

__device__ __forceinline__ void lds_load16(void* lds, const void* g) {
  __builtin_amdgcn_global_load_lds(
      (const __attribute__((address_space(1))) uint32_t*)(uintptr_t)g,
      (__attribute__((address_space(3))) uint32_t*)(uint32_t)(uintptr_t)lds,
      16, 0, 0);
}

// ---- K_front: three independent jobs in one launch (saves 2 launch gaps):
//  blocks 0..2047    : k_prep  (Wp = bf16(gamma⊙Wout), c1, c2)
//  blocks 2048..3583 : k_kvwq  (k, v, wq = memory @ W.T)
//  blocks 3584..3743 : zero PRT (replaces hipMemsetAsync)
__global__ __launch_bounds__(256) void k_front(
    const float* __restrict__ wro, const float* __restrict__ gamma,
    const float* __restrict__ beta, unsigned short* __restrict__ wp,
    float* __restrict__ c1, float* __restrict__ c2,
    const float* __restrict__ mem, const float* __restrict__ wrk,
    const float* __restrict__ wrv, const float* __restrict__ wwq,
    float* __restrict__ kbuf, float* __restrict__ vbuf,
    float* __restrict__ wqbuf, float* __restrict__ PRT) {
  __shared__ float red1[4], red2[4];
  const int b = blockIdx.x;
  const int tid = threadIdx.x;
  if (b < 2048) {
    // ---- prep
    int j = b;
    int d = tid * 8;
    const float* src = wro + (size_t)j * D_ + d;
    f32x4 a = *(const f32x4*)src, bb = *(const f32x4*)(src + 4);
    f32x4 g0 = *(const f32x4*)(gamma + d), g1 = *(const f32x4*)(gamma + d + 4);
    f32x4 b0 = *(const f32x4*)(beta + d), b1 = *(const f32x4*)(beta + d + 4);
    ushort4 o0, o1;
    o0.x = f2bf(a[0] * g0[0]); o0.y = f2bf(a[1] * g0[1]);
    o0.z = f2bf(a[2] * g0[2]); o0.w = f2bf(a[3] * g0[3]);
    o1.x = f2bf(bb[0] * g1[0]); o1.y = f2bf(bb[1] * g1[1]);
    o1.z = f2bf(bb[2] * g1[2]); o1.w = f2bf(bb[3] * g1[3]);
    unsigned short* dst = wp + (size_t)j * D_ + d;
    *(ushort4*)dst = o0;
    *(ushort4*)(dst + 4) = o1;
    float s1 = a[0] * g0[0] + a[1] * g0[1] + a[2] * g0[2] + a[3] * g0[3] +
               bb[0] * g1[0] + bb[1] * g1[1] + bb[2] * g1[2] + bb[3] * g1[3];
    float s2 = a[0] * b0[0] + a[1] * b0[1] + a[2] * b0[2] + a[3] * b0[3] +
               bb[0] * b1[0] + bb[1] * b1[1] + bb[2] * b1[2] + bb[3] * b1[3];
#pragma unroll
    for (int off = 1; off < 64; off <<= 1) {
      s1 += __shfl_xor(s1, off, 64);
      s2 += __shfl_xor(s2, off, 64);
    }
    int wave = tid >> 6, lane = tid & 63;
    if (lane == 0) { red1[wave] = s1; red2[wave] = s2; }
    __syncthreads();
    if (tid == 0) {
      c1[j] = red1[0] + red1[1] + red1[2] + red1[3];
      c2[j] = red2[0] + red2[1] + red2[2] + red2[3];
    }
  } else if (b < 3584) {
    // ---- kvwq
    int gw = ((b - 2048) * 256 + tid) >> 6;  // 0..6143
    int lane = tid & 63;
    int which = gw >> 11;
    int j = gw & 2047;
    const float* W = which == 0 ? wrk : (which == 1 ? wrv : wwq);
    float* O = which == 0 ? kbuf : (which == 1 ? vbuf : wqbuf);
    const f32x4* Wrow = (const f32x4*)(W + (size_t)j * D_);
    const f32x4* M4 = (const f32x4*)mem;
    float acc[8];
#pragma unroll
    for (int kk = 0; kk < 8; ++kk) acc[kk] = 0.f;
#pragma unroll
    for (int t = 0; t < 8; ++t) {
      f32x4 w4 = Wrow[lane + 64 * t];
#pragma unroll
      for (int kk = 0; kk < 8; ++kk) {
        f32x4 m4 = M4[kk * 512 + lane + 64 * t];
        acc[kk] += w4[0] * m4[0] + w4[1] * m4[1] + w4[2] * m4[2] + w4[3] * m4[3];
      }
    }
#pragma unroll
    for (int off = 1; off < 64; off <<= 1)
#pragma unroll
      for (int kk = 0; kk < 8; ++kk) acc[kk] += __shfl_xor(acc[kk], off, 64);
    if (lane == 0) {
#pragma unroll
      for (int kk = 0; kk < 8; ++kk) O[kk * D_ + j] = acc[kk];
    }
  } else {
    // ---- zero PRT (80*2048 floats = 40960 f32x4)
    int idx = (b - 3584) * 256 + tid;
    ((f32x4*)PRT)[idx] = (f32x4){0.f, 0.f, 0.f, 0.f};
  }
}

// ---- K2: PRT[80][2048] fp32 via atomics. 8-way j-split: 1024 blocks,
// 32-iter chains.
__global__ __launch_bounds__(256) void k_pr(
    const float* __restrict__ wrq, const float* __restrict__ wwk,
    const float* __restrict__ kbuf, const float* __restrict__ wqbuf,
    float* __restrict__ PRT) {
  int b = blockIdx.x;            // 0..1023
  int tid = threadIdx.x;
  bool isP = b < 512;
  int bb = isP ? b : b - 512;
  int oct = bb & 7;              // j eighth
  int sub = (bb >> 3) & 7;       // h (P) or jc (R)
  int ic = bb >> 6;
  int i = ic * 256 + tid;
  const float* W = isP ? wrq : wwk;
  const float* V = isP ? kbuf : wqbuf;
  float scale = isP ? SCALE_R : SCALE_W;
  int rowbase = isP ? sub * 8 : 64;
  float acc[8];
#pragma unroll
  for (int kk = 0; kk < 8; ++kk) acc[kk] = 0.f;
  int j0 = sub * 256 + oct * 32;
#pragma unroll 4
  for (int jj = 0; jj < 32; ++jj) {
    int j = j0 + jj;
    float wv = W[(size_t)j * D_ + i];
#pragma unroll
    for (int kk = 0; kk < 8; ++kk) acc[kk] += wv * V[kk * D_ + j];
  }
#pragma unroll
  for (int kk = 0; kk < 8; ++kk)
    atomicAdd(&PRT[(rowbase + kk) * D_ + i], acc[kk] * scale);
}

// ---- convert PRT fp32 -> PRTb bf16 (after all k_pr atomics)
__global__ __launch_bounds__(256) void k_prtb(const float* __restrict__ PRT,
                                              unsigned short* __restrict__ PRTb) {
  int i = (blockIdx.x * 256 + threadIdx.x) * 4;
  f32x4 v = *(const f32x4*)(PRT + i);
  ushort4 o = {f2bf(v[0]), f2bf(v[1]), f2bf(v[2]), f2bf(v[3])};
  *(ushort4*)(PRTb + i) = o;
}

// ---- K3: fused MFMA S-GEMM + in-reg PER-HEAD softmax + ro + (raw ro, mu, rstd) + u-partials
__global__ __launch_bounds__(256) void k_main(
    const float* __restrict__ hidden, const unsigned short* __restrict__ PRTb,
    const float* __restrict__ vbuf,
    unsigned short* __restrict__ Xhat, float* __restrict__ mu_out,
    float* __restrict__ rstd_out,
    float* __restrict__ upart, float* __restrict__ Zpart) {
  __shared__ unsigned short Ah[2][64 * 64];   // 16 KB, XOR-swizzled bf16 hidden tile
  __shared__ unsigned short Bh[2][80 * 64];   // 20 KB, XOR-swizzled bf16 PRT tile
  __shared__ unsigned short attnL[64 * 64];   // 8 KB bf16 attn
  __shared__ float e8lds[64][8];              // 2 KB
  const int tid = threadIdx.x;
  const int row0 = blockIdx.x * 64;
  const int wave = tid >> 6, lane = tid & 63;
  const int fl = lane & 15, fk = lane >> 4;
  const int ar = tid >> 2, acg = tid & 3;     // A staging: row, 16-col group

  f32x4 sA0[4], sA1[4];

  auto loadA = [&](f32x4* a, int t) {
    const float* srcA = hidden + (size_t)(row0 + ar) * D_ + t * 64 + acg * 16;
#pragma unroll
    for (int q = 0; q < 4; ++q) a[q] = *(const f32x4*)(srcA + q * 4);
  };
  auto writeA = [&](int buf, f32x4* a) {
#pragma unroll
    for (int hh = 0; hh < 2; ++hh) {
      f32x4 x = a[hh * 2], y = a[hh * 2 + 1];
      ushort4 o0 = {f2bf(x[0]), f2bf(x[1]), f2bf(x[2]), f2bf(x[3])};
      ushort4 o1 = {f2bf(y[0]), f2bf(y[1]), f2bf(y[2]), f2bf(y[3])};
      int idx = (ar * 64 + acg * 16 + hh * 8) ^ ((ar & 7) << 3);
      *(ushort4*)&Ah[buf][idx] = o0;
      *(ushort4*)&Ah[buf][idx + 4] = o1;
    }
  };
  auto stageB = [&](int buf, int kt) {  // 640 x 16B granules over [80][64] bf16
#pragma unroll
    for (int s = 0; s < 2; ++s) {
      int e = s * 256 + tid;
      int rB = e >> 3, gl = e & 7, gs = gl ^ (rB & 7);
      lds_load16(&Bh[buf][rB * 64 + gl * 8],
                 PRTb + (size_t)rB * D_ + kt * 64 + gs * 8);
    }
    if (tid < 128) {
      int e = 512 + tid;
      int rB = e >> 3, gl = e & 7, gs = gl ^ (rB & 7);
      lds_load16(&Bh[buf][rB * 64 + gl * 8],
                 PRTb + (size_t)rB * D_ + kt * 64 + gs * 8);
    }
  };

  f32x4 acc[5];
#pragma unroll
  for (int n = 0; n < 5; ++n) acc[n] = (f32x4){0.f, 0.f, 0.f, 0.f};

  auto compute = [&](int buf) {
#pragma unroll
    for (int kk = 0; kk < 2; ++kk) {
      int klo = kk * 32 + fk * 8;
      bf16x8 af = *(const bf16x8*)&Ah[buf][((wave * 16 + fl) * 64 + klo) ^ ((fl & 7) << 3)];
#pragma unroll
      for (int n = 0; n < 5; ++n) {
        bf16x8 bf = *(const bf16x8*)&Bh[buf][((n * 16 + fl) * 64 + klo) ^ ((fl & 7) << 3)];
        acc[n] = __builtin_amdgcn_mfma_f32_16x16x32_bf16(af, bf, acc[n], 0, 0, 0);
      }
    }
  };

  loadA(sA0, 0);
  loadA(sA1, 1);
  stageB(0, 0);
  for (int t = 0; t < 32; t += 2) {
    writeA(0, sA0);
    if (t + 2 < 32) loadA(sA0, t + 2);
    __syncthreads();          // (a): Ah0+Bh0(t) ready; all waves done reading Bh1(t-1)
    stageB(1, t + 1);         // t+1 <= 31 always
    compute(0);               // tile t
    writeA(1, sA1);
    if (t + 3 < 32) loadA(sA1, t + 3);
    __syncthreads();          // (b): Ah1+Bh1(t+1) ready; all waves done reading Bh0(t)
    if (t + 2 < 32) stageB(0, t + 2);
    compute(1);               // tile t+1
  }

  // ---- in-register PER-HEAD softmax.
#pragma unroll
  for (int r = 0; r < 4; ++r) {
    int rowl = wave * 16 + fk * 4 + r;
#pragma unroll
    for (int n = 0; n < 4; ++n) {
      float sv = acc[n][r];
      float m = sv;
      m = fmaxf(m, __shfl_xor(m, 1, 64));
      m = fmaxf(m, __shfl_xor(m, 2, 64));
      m = fmaxf(m, __shfl_xor(m, 4, 64));
      float e = __expf(sv - m);
      float ssum = e;
      ssum += __shfl_xor(ssum, 1, 64);
      ssum += __shfl_xor(ssum, 2, 64);
      ssum += __shfl_xor(ssum, 4, 64);
      attnL[rowl * 64 + n * 16 + fl] = f2bf(e / ssum);
    }
    if (fl < 8) e8lds[rowl][fl] = __expf(acc[4][r]);  // write-softmax numerator (|s_w|<<1)
  }
  __syncthreads();

  // ---- ro phase: per wave 16 rows; chunk c = head, d = c*256 + lane*4
  float ssum[16], ssq[16];
#pragma unroll
  for (int rw = 0; rw < 16; ++rw) { ssum[rw] = 0.f; ssq[rw] = 0.f; }
#pragma unroll
  for (int c = 0; c < 8; ++c) {
    int d0 = c * 256 + lane * 4;
    f32x4 vv[8];
#pragma unroll
    for (int kk = 0; kk < 8; ++kk) vv[kk] = *(const f32x4*)(vbuf + kk * D_ + d0);
#pragma unroll
    for (int rw = 0; rw < 16; ++rw) {
      bf16x8 at = *(const bf16x8*)&attnL[(wave * 16 + rw) * 64 + c * 8];
      f32x4 ro = (float)at[0] * vv[0] + (float)at[1] * vv[1] +
                 (float)at[2] * vv[2] + (float)at[3] * vv[3] +
                 (float)at[4] * vv[4] + (float)at[5] * vv[5] +
                 (float)at[6] * vv[6] + (float)at[7] * vv[7];
      ssum[rw] += ro[0] + ro[1] + ro[2] + ro[3];
      ssq[rw] += ro[0] * ro[0] + ro[1] * ro[1] + ro[2] * ro[2] + ro[3] * ro[3];
      ushort4 o = {f2bf(ro[0]), f2bf(ro[1]), f2bf(ro[2]), f2bf(ro[3])};
      *(ushort4*)(Xhat + (size_t)(row0 + wave * 16 + rw) * D_ + d0) = o;
    }
  }
  float muv = 0.f, rstdv = 0.f;
#pragma unroll
  for (int rw = 0; rw < 16; ++rw) {
    float s = ssum[rw], q = ssq[rw];
#pragma unroll
    for (int off = 1; off < 64; off <<= 1) {
      s += __shfl_xor(s, off, 64);
      q += __shfl_xor(q, off, 64);
    }
    float m = s * (1.f / 2048.f);
    float var = q * (1.f / 2048.f) - m * m;
    float rs = rsqrtf(var + 1e-5f);
    if (lane == rw) { muv = m; rstdv = rs; }
  }
  if (lane < 16) {
    mu_out[row0 + wave * 16 + lane] = muv;
    rstd_out[row0 + wave * 16 + lane] = rstdv;
  }
  __syncthreads();

  // ---- u-partials: wave owns 512-wide d-range, 8-row load strips
  for (int dt = 0; dt < 2; ++dt) {
    int d0 = wave * 512 + dt * 256 + lane * 4;
    f32x4 ua[8];
#pragma unroll
    for (int kk = 0; kk < 8; ++kk) ua[kk] = (f32x4){0.f, 0.f, 0.f, 0.f};
    for (int r8 = 0; r8 < 64; r8 += 8) {
      f32x4 hv[8];
#pragma unroll
      for (int q = 0; q < 8; ++q)
        hv[q] = *(const f32x4*)(hidden + (size_t)(row0 + r8 + q) * D_ + d0);
#pragma unroll
      for (int q = 0; q < 8; ++q) {
        f32x4 e0 = *(const f32x4*)&e8lds[r8 + q][0];
        f32x4 e1 = *(const f32x4*)&e8lds[r8 + q][4];
        ua[0] += e0[0] * hv[q]; ua[1] += e0[1] * hv[q];
        ua[2] += e0[2] * hv[q]; ua[3] += e0[3] * hv[q];
        ua[4] += e1[0] * hv[q]; ua[5] += e1[1] * hv[q];
        ua[6] += e1[2] * hv[q]; ua[7] += e1[3] * hv[q];
      }
    }
#pragma unroll
    for (int kk = 0; kk < 8; ++kk)
      *(f32x4*)(upart + ((size_t)blockIdx.x * 8 + kk) * D_ + d0) = ua[kk];
  }
  if (tid < 8) {
    float z = 0.f;
    for (int r = 0; r < 64; ++r) z += e8lds[r][tid];
    Zpart[blockIdx.x * 8 + tid] = z;
  }
}

// ---- K4: reduce u-partials, t = u/Z. 256 blocks, 4 threads/output, LDS combine.
__global__ __launch_bounds__(256) void k_ured(const float* __restrict__ upart,
                                              const float* __restrict__ Zpart,
                                              float* __restrict__ tbuf) {
  __shared__ float us[256], zs[256];
  int tid = threadIdx.x;
  int q = tid >> 6;                       // partial quarter 0..3
  int o = blockIdx.x * 64 + (tid & 63);   // output 0..16383
  int kk = o >> 11, d = o & 2047;
  float z = 0.f, u = 0.f;
#pragma unroll 4
  for (int b = q * 64; b < q * 64 + 64; ++b) {
    z += Zpart[b * 8 + kk];
    u += upart[((size_t)b * 8 + kk) * 2048 + d];
  }
  us[tid] = u; zs[tid] = z;
  __syncthreads();
  if (q == 0) {
    u += us[tid + 64] + us[tid + 128] + us[tid + 192];
    z += zs[tid + 64] + zs[tid + 128] + zs[tid + 192];
    tbuf[o] = u / z;
  }
}

// ---- K_big: blocks 0..2047 = gemm (R10-locked structure), blocks 2048..2559 =
// newmem (independent of gemm output; rides inside gemm's window).
__global__ __launch_bounds__(256) void k_big(
    const unsigned short* __restrict__ A,  // raw ro bf16 [16384][2048]
    const unsigned short* __restrict__ B,  // W' bf16 [2048][2048] (row j = out col)
    const float* __restrict__ hidden, const float* __restrict__ gate,
    const float* __restrict__ mu, const float* __restrict__ rstd,
    const float* __restrict__ c1, const float* __restrict__ c2,
    float* __restrict__ out,
    const float* __restrict__ tbuf, const float* __restrict__ wwv,
    const float* __restrict__ mem, const float* __restrict__ wgate,
    float* __restrict__ out_mem) {
  __shared__ unsigned short As[2][128 * 64];
  __shared__ unsigned short Bs[2][128 * 64];
  const int tid = threadIdx.x;
  if (blockIdx.x >= 2048) {
    // ---- newmem: new_memory = (1-wg)*memory + wg * (t @ Wwv.T)
    int vb = blockIdx.x - 2048;
    int j = (vb * 256 + tid) >> 6;  // 0..2047
    int lane = tid & 63;
    const f32x4* Wrow = (const f32x4*)(wwv + (size_t)j * D_);
    const f32x4* T4 = (const f32x4*)tbuf;
    float acc[8];
#pragma unroll
    for (int kk = 0; kk < 8; ++kk) acc[kk] = 0.f;
#pragma unroll
    for (int t = 0; t < 8; ++t) {
      f32x4 w4 = Wrow[lane + 64 * t];
#pragma unroll
      for (int kk = 0; kk < 8; ++kk) {
        f32x4 t4 = T4[kk * 512 + lane + 64 * t];
        acc[kk] += w4[0] * t4[0] + w4[1] * t4[1] + w4[2] * t4[2] + w4[3] * t4[3];
      }
    }
#pragma unroll
    for (int off = 1; off < 64; off <<= 1)
#pragma unroll
      for (int kk = 0; kk < 8; ++kk) acc[kk] += __shfl_xor(acc[kk], off, 64);
    if (lane == 0) {
      float wg = 1.f / (1.f + __expf(-wgate[0]));
#pragma unroll
      for (int kk = 0; kk < 8; ++kk)
        out_mem[kk * D_ + j] = (1.f - wg) * mem[kk * D_ + j] + wg * acc[kk];
    }
    return;
  }
  // ---- gemm: result = hidden + g*(rstd*(ro@W'^T) - rstd*mu*c1 + c2)
  const int bm = blockIdx.x >> 4, bn = blockIdx.x & 15;
  const int row0 = bm * 128, col0 = bn * 128;
  const int wave = tid >> 6, lane = tid & 63;
  const int wr = wave >> 1, wc = wave & 1;
  const int fl = lane & 15, fk = lane >> 4;
  const int srow = tid >> 3;
  const int scol_l = (tid & 7) * 8;                 // linear LDS dest col
  const int scol_g = ((tid & 7) ^ (srow & 7)) * 8;  // pre-swizzled global col

  f32x4 acc[4][4];
#pragma unroll
  for (int m = 0; m < 4; ++m)
#pragma unroll
    for (int n = 0; n < 4; ++n) acc[m][n] = (f32x4){0.f, 0.f, 0.f, 0.f};

  auto stage = [&](int buf, int kt) {
    const int k0 = kt * 64;
#pragma unroll
    for (int p = 0; p < 4; ++p) {
      int r = srow + p * 32;  // (r&7) == (srow&7)
      lds_load16(&As[buf][r * 64 + scol_l], A + (size_t)(row0 + r) * D_ + k0 + scol_g);
      lds_load16(&Bs[buf][r * 64 + scol_l], B + (size_t)(col0 + r) * D_ + k0 + scol_g);
    }
  };

  stage(0, 0);
  for (int kt = 0; kt < 32; ++kt) {
    __syncthreads();  // stage(kt) complete (drains vmcnt)
    if (kt + 1 < 32) stage((kt + 1) & 1, kt + 1);
    const int cb = kt & 1;
#pragma unroll
    for (int kkk = 0; kkk < 2; ++kkk) {
      const int gsw = ((kkk * 4 + fk) ^ (fl & 7)) * 8;
      bf16x8 af[4], bfr[4];
#pragma unroll
      for (int m = 0; m < 4; ++m)
        af[m] = *(const bf16x8*)&As[cb][(wr * 64 + m * 16 + fl) * 64 + gsw];
#pragma unroll
      for (int n = 0; n < 4; ++n)
        bfr[n] = *(const bf16x8*)&Bs[cb][(wc * 64 + n * 16 + fl) * 64 + gsw];
#pragma unroll
      for (int m = 0; m < 4; ++m)
#pragma unroll
        for (int n = 0; n < 4; ++n)
          acc[m][n] = __builtin_amdgcn_mfma_f32_16x16x32_bf16(af[m], bfr[n], acc[m][n], 0, 0, 0);
    }
  }
  float g = 1.f / (1.f + __expf(-gate[0]));
  int cols[4];
  float C1v[4], C2v[4];
#pragma unroll
  for (int n = 0; n < 4; ++n) {
    cols[n] = col0 + wc * 64 + n * 16 + fl;
    C1v[n] = c1[cols[n]] * g;
    C2v[n] = c2[cols[n]] * g;
  }
#pragma unroll
  for (int m = 0; m < 4; ++m)
#pragma unroll
    for (int r = 0; r < 4; ++r) {
      int row = row0 + wr * 64 + m * 16 + fk * 4 + r;
      float RS = rstd[row], MU = mu[row];
      const float* hrow = hidden + (size_t)row * D_;
      float* orow = out + (size_t)row * D_;
#pragma unroll
      for (int n = 0; n < 4; ++n)
        orow[cols[n]] = hrow[cols[n]] + g * RS * acc[m][n][r] - RS * MU * C1v[n] + C2v[n];
    }
}

extern "C" void kernel_launch(void* const* d_in, const int* in_sizes, int n_in,
                              void* d_out, int out_size, void* d_ws, size_t ws_size,
                              hipStream_t stream) {
  const float* hidden = (const float*)d_in[0];
  const float* mem    = (const float*)d_in[1];
  const float* wrq = (const float*)d_in[2];
  const float* wrk = (const float*)d_in[3];
  const float* wrv = (const float*)d_in[4];
  const float* wro = (const float*)d_in[5];
  const float* wwq = (const float*)d_in[6];
  const float* wwk = (const float*)d_in[7];
  const float* wwv = (const float*)d_in[8];
  const float* gamma = (const float*)d_in[9];
  const float* beta  = (const float*)d_in[10];
  const float* gate  = (const float*)d_in[11];
  const float* wgate = (const float*)d_in[12];
  float* out = (float*)d_out;

  char* ws = (char*)d_ws;
  float* kbuf  = (float*)(ws);                    // 64 KB; reused as mu after k_pr
  float* vbuf  = (float*)(ws + (64 << 10));       // 64 KB
  float* wqbuf = (float*)(ws + (128 << 10));      // 64 KB; reused as rstd after k_pr
  float* PRT   = (float*)(ws + (192 << 10));      // 640 KB fp32
  float* tbuf  = (float*)(ws + (832 << 10));      // 64 KB
  float* Zpart = (float*)(ws + (896 << 10));      // 8 KB
  float* c1    = (float*)(ws + (904 << 10));      // 8 KB
  float* c2    = (float*)(ws + (912 << 10));      // 8 KB
  unsigned short* PRTb = (unsigned short*)(ws + (960 << 10));  // 320 KB bf16
  float* upart = (float*)(ws + (1536ull << 10));  // 16 MB
  unsigned short* Wp   = (unsigned short*)(ws + (1536ull << 10) + (16ull << 20));  // 8 MB
  unsigned short* Xhat = (unsigned short*)(ws + (1536ull << 10) + (24ull << 20));  // 64 MB
  float* mu   = kbuf;    // overlay: kbuf dead after k_pr
  float* rstd = wqbuf;   // overlay: wqbuf dead after k_pr

  k_front<<<3744, 256, 0, stream>>>(wro, gamma, beta, Wp, c1, c2,
                                    mem, wrk, wrv, wwq, kbuf, vbuf, wqbuf, PRT);
  k_pr<<<1024, 256, 0, stream>>>(wrq, wwk, kbuf, wqbuf, PRT);
  k_prtb<<<160, 256, 0, stream>>>(PRT, PRTb);
  k_main<<<256, 256, 0, stream>>>(hidden, PRTb, vbuf, Xhat, mu, rstd, upart, Zpart);
  k_ured<<<256, 256, 0, stream>>>(upart, Zpart, tbuf);
  k_big<<<2560, 256, 0, stream>>>(Xhat, Wp, hidden, gate, mu, rstd, c1, c2, out,
                                  tbuf, wwv, mem, wgate, out + (size_t)N_ * D_);
}